// Round 3
// baseline (1207.662 us; speedup 1.0000x reference)
//
#include <hip/hip_runtime.h>
#include <hip/hip_bf16.h>
#include <math.h>

#define N_NODES 40000
#define N_EDGES 400000
#define GCLIP 511

using short8  = __attribute__((ext_vector_type(8))) short;
using ushort8 = __attribute__((ext_vector_type(8))) unsigned short;
using floatx4 = __attribute__((ext_vector_type(4))) float;

__device__ __forceinline__ void split_bf16(float v, unsigned short& hi, unsigned short& lo) {
    __hip_bfloat16 h = __float2bfloat16(v);
    float r = v - __bfloat162float(h);
    __hip_bfloat16 l = __float2bfloat16(r);
    hi = *(unsigned short*)&h;
    lo = *(unsigned short*)&l;
}
__device__ __forceinline__ unsigned short f2bf(float f) {
    __hip_bfloat16 h = __float2bfloat16(f);
    return *(unsigned short*)&h;
}
__device__ __forceinline__ float bf2f(unsigned short u) {
    __hip_bfloat16 h = *(__hip_bfloat16*)&u;
    return __bfloat162float(h);
}
__device__ __forceinline__ floatx4 mfma16(short8 a, short8 b, floatx4 c) {
    return __builtin_amdgcn_mfma_f32_16x16x32_bf16(a, b, c, 0, 0, 0);
}

// ---------------- CSR build ----------------
__global__ void count_kernel(const int* __restrict__ dst, int* __restrict__ cnt, int E) {
    int e = blockIdx.x * 256 + threadIdx.x;
    if (e < E) atomicAdd(&cnt[dst[e]], 1);
}

// phase 1: per-block (1024) exclusive scan -> partial rowp + block sums
__global__ void scan1_kernel(const int* __restrict__ cnt, int* __restrict__ rowp,
                             int* __restrict__ bsum, int n) {
    __shared__ int wsum[16];
    __shared__ int woff[16];
    int tid = threadIdx.x, wave = tid >> 6, lane = tid & 63;
    int i = blockIdx.x * 1024 + tid;
    int v = (i < n) ? cnt[i] : 0;
    int x = v;
    for (int off = 1; off < 64; off <<= 1) {
        int t = __shfl_up(x, off);
        if (lane >= off) x += t;
    }
    if (lane == 63) wsum[wave] = x;
    __syncthreads();
    if (wave == 0 && lane < 16) {
        int s = wsum[lane];
        for (int off = 1; off < 16; off <<= 1) {
            int t = __shfl_up(s, off);
            if (lane >= off) s += t;
        }
        woff[lane] = s;
    }
    __syncthreads();
    int incl = x + ((wave == 0) ? 0 : woff[wave - 1]);
    if (i < n) rowp[i] = incl - v;
    if (tid == 0) bsum[blockIdx.x] = 0;   // init
    __syncthreads();
    if (tid == 1023) bsum[blockIdx.x] = incl;
}

// phase 2: scan 40 block sums (one wave), also writes rowp[n]
__global__ void scan2_kernel(const int* __restrict__ bsum, int* __restrict__ boffs,
                             int* __restrict__ rowp, int nb, int n) {
    int lane = threadIdx.x;
    int v = (lane < nb) ? bsum[lane] : 0;
    int x = v;
    for (int off = 1; off < 64; off <<= 1) {
        int t = __shfl_up(x, off);
        if (lane >= off) x += t;
    }
    if (lane < nb) boffs[lane] = x - v;
    if (lane == nb - 1) rowp[n] = x;
}

// phase 3: add block offsets, init cursor
__global__ void scan3_kernel(int* __restrict__ rowp, int* __restrict__ curs,
                             const int* __restrict__ boffs, int n) {
    int i = blockIdx.x * 1024 + threadIdx.x;
    if (i < n) {
        int v = rowp[i] + boffs[blockIdx.x];
        rowp[i] = v;
        curs[i] = v;
    }
}

__global__ void scatter_kernel(const int* __restrict__ src, const int* __restrict__ dst,
                               int* __restrict__ cursor, int2* __restrict__ csr2, int E) {
    int e = blockIdx.x * 256 + threadIdx.x;
    if (e < E) {
        int pos = atomicAdd(&cursor[dst[e]], 1);
        csr2[pos] = make_int2(src[e], e);
    }
}

// ---------------- feature build -> bf16 hi/lo planes [N][32] (cols 16..31 zero) -------
__global__ void feat_kernel(const float* __restrict__ x, const int* __restrict__ batch,
                            const int* __restrict__ gptr, const int* __restrict__ tgid,
                            const float* __restrict__ gp, const float* __restrict__ sp,
                            const float* __restrict__ ep,
                            unsigned short* __restrict__ fhi, unsigned short* __restrict__ flo,
                            int n) {
    int idx = blockIdx.x * 256 + threadIdx.x;
    if (idx >= n * 32) return;
    int node = idx >> 5, c = idx & 31;
    float v = 0.f;
    if (c < 4) {
        v = x[node * 4 + c];
    } else if (c < 7) {
        int gid = gptr[batch[node]] + tgid[node];
        gid = min(max(gid, 0), GCLIP);
        v = gp[gid * 3 + (c - 4)];
    } else if (c < 10) {
        v = sp[node * 3 + (c - 7)];
    } else if (c < 16) {
        int gid = gptr[batch[node]] + tgid[node];
        gid = min(max(gid, 0), GCLIP);
        v = ep[gid * 6 + (c - 10)];
    }
    unsigned short hi, lo;
    split_bf16(v, hi, lo);
    fhi[idx] = hi;
    flo[idx] = lo;
}

// ---------------- weight prep: transpose to [Nrows][Ka] bf16 (hi only) ----------------
#define WOFF_WIN 0
#define WOFF_QKV 6144
#define WOFF_WO  337920
#define WOFF_WF1 448512
#define WOFF_WF2 669696
#define WOFF_HSD 890880
#define WOFF_WE2 964608
#define WTOT     983040

__global__ void prep_kernel(const float* __restrict__ W_in, const float* __restrict__ Wq,
                            const float* __restrict__ Wk, const float* __restrict__ Wv,
                            const float* __restrict__ Wo, const float* __restrict__ Wf1,
                            const float* __restrict__ Wf2, const float* __restrict__ We1,
                            const float* __restrict__ We2, unsigned short* __restrict__ wb) {
    int idx = blockIdx.x * 256 + threadIdx.x;
    if (idx >= WTOT) return;
    float val;
    if (idx < WOFF_QKV) {                       // W_in^T [192][32], K=16 padded
        int n = idx / 32, k = idx % 32;
        val = (k < 16) ? W_in[k * 192 + n] : 0.f;
    } else if (idx < WOFF_WO) {                 // Wqkv^T [576][192] x3
        int r = idx - WOFF_QKV; int l = r / 110592; r %= 110592;
        int n = r / 192, k = r % 192;
        const float* s = (n < 192) ? Wq : (n < 384 ? Wk : Wv);
        val = s[l * 36864 + k * 192 + (n % 192)];
    } else if (idx < WOFF_WF1) {                // Wo^T [192][192] x3
        int r = idx - WOFF_WO; int l = r / 36864; r %= 36864;
        int n = r / 192, k = r % 192;
        val = Wo[l * 36864 + k * 192 + n];
    } else if (idx < WOFF_WF2) {                // Wf1^T [384][192] x3
        int r = idx - WOFF_WF1; int l = r / 73728; r %= 73728;
        int n = r / 192, k = r % 192;
        val = Wf1[l * 73728 + k * 384 + n];
    } else if (idx < WOFF_HSD) {                // Wf2^T [192][384] x3
        int r = idx - WOFF_WF2; int l = r / 73728; r %= 73728;
        int n = r / 384, k = r % 384;
        val = Wf2[l * 73728 + k * 192 + n];
    } else if (idx < WOFF_WE2) {                // [Hs|Hd]^T [384][192]
        int r = idx - WOFF_HSD;
        int n = r / 192, k = r % 192;
        val = (n < 192) ? We1[k * 192 + n] : We1[(192 + k) * 192 + (n - 192)];
    } else {                                    // We2^T [96][192]
        int r = idx - WOFF_WE2;
        int n = r / 192, k = r % 192;
        val = We2[k * 96 + n];
    }
    wb[idx] = f2bf(val);
}

// ---------------- LDS-free MFMA GEMM ---------------------------------------------------
// A pre-split bf16 hi/lo planes [M][Ka]; B bf16 [ncols][Ka]. 2-term: Ahi*B + Alo*B.
// block 256 = 4 waves; wave = 32 rows x 192 cols (2x12 16x16 tiles). grid(ceil(M/128), ncols/192)
// EPI: 0 none, 1 relu, 2 bias+resid+LN (grid.y==1, ldc==192). DUAL: 1 -> write hi/lo planes.
template <int EPI, int DUAL>
__global__ __launch_bounds__(256, 2)
void mfma_gemm(const unsigned short* __restrict__ Ahi, const unsigned short* __restrict__ Alo,
               int M, int Ka,
               const unsigned short* __restrict__ Bhi, const float* __restrict__ bias,
               const unsigned short* __restrict__ Rhi, const unsigned short* __restrict__ Rlo,
               const float* __restrict__ lng, const float* __restrict__ lnb,
               unsigned short* __restrict__ Chi, unsigned short* __restrict__ Clo, int ldc) {
    const int tid = threadIdx.x;
    const int wave = tid >> 6, lane = tid & 63;
    const int quad = lane >> 4, l16 = lane & 15;
    const int rbase = blockIdx.x * 128;
    const int cbase = blockIdx.y * 192;

    floatx4 acc[2][12];
#pragma unroll
    for (int mt = 0; mt < 2; ++mt)
#pragma unroll
        for (int nt = 0; nt < 12; ++nt) acc[mt][nt] = (floatx4)0.0f;

    const int r0 = min(rbase + wave * 32 + l16, M - 1);
    const int r1 = min(rbase + wave * 32 + 16 + l16, M - 1);
    const unsigned short* pa0h = Ahi + (size_t)r0 * Ka + quad * 8;
    const unsigned short* pa0l = Alo + (size_t)r0 * Ka + quad * 8;
    const unsigned short* pa1h = Ahi + (size_t)r1 * Ka + quad * 8;
    const unsigned short* pa1l = Alo + (size_t)r1 * Ka + quad * 8;
    const unsigned short* pb   = Bhi + (size_t)(cbase + l16) * Ka + quad * 8;

    for (int kc = 0; kc < Ka; kc += 32) {
        short8 ah0 = *(const short8*)(pa0h + kc);
        short8 al0 = *(const short8*)(pa0l + kc);
        short8 ah1 = *(const short8*)(pa1h + kc);
        short8 al1 = *(const short8*)(pa1l + kc);
#pragma unroll
        for (int nt = 0; nt < 12; ++nt) {
            short8 b = *(const short8*)(pb + nt * 16 * Ka + kc);
            acc[0][nt] = mfma16(ah0, b, acc[0][nt]);
            acc[0][nt] = mfma16(al0, b, acc[0][nt]);
            acc[1][nt] = mfma16(ah1, b, acc[1][nt]);
            acc[1][nt] = mfma16(al1, b, acc[1][nt]);
        }
    }

    float bb[12], gg[12], be[12];
#pragma unroll
    for (int nt = 0; nt < 12; ++nt) {
        int col = cbase + nt * 16 + l16;
        bb[nt] = bias ? bias[col] : 0.f;
        if (EPI == 2) { gg[nt] = lng[col]; be[nt] = lnb[col]; }
    }
#pragma unroll
    for (int mt = 0; mt < 2; ++mt) {
#pragma unroll
        for (int reg = 0; reg < 4; ++reg) {
            int row = rbase + wave * 32 + mt * 16 + quad * 4 + reg;
            if (EPI == 2) {
                int rr = min(row, M - 1);
                float v[12], s = 0.f, q = 0.f;
#pragma unroll
                for (int nt = 0; nt < 12; ++nt) {
                    size_t off = (size_t)rr * 192 + nt * 16 + l16;
                    float resid = bf2f(Rhi[off]) + bf2f(Rlo[off]);
                    v[nt] = acc[mt][nt][reg] + bb[nt] + resid;
                    s += v[nt]; q += v[nt] * v[nt];
                }
#pragma unroll
                for (int off = 1; off < 16; off <<= 1) {
                    s += __shfl_xor(s, off);
                    q += __shfl_xor(q, off);
                }
                float mean = s * (1.f / 192.f);
                float var = q * (1.f / 192.f) - mean * mean;
                float rs = rsqrtf(var + 1e-5f);
                if (row < M) {
#pragma unroll
                    for (int nt = 0; nt < 12; ++nt) {
                        float r = (v[nt] - mean) * rs * gg[nt] + be[nt];
                        unsigned short hi, lo;
                        split_bf16(r, hi, lo);
                        size_t off = (size_t)row * 192 + nt * 16 + l16;
                        Chi[off] = hi; Clo[off] = lo;
                    }
                }
            } else if (row < M) {
#pragma unroll
                for (int nt = 0; nt < 12; ++nt) {
                    float v = acc[mt][nt][reg] + bb[nt];
                    if (EPI == 1) v = fmaxf(v, 0.f);
                    size_t off = (size_t)row * ldc + cbase + nt * 16 + l16;
                    if (DUAL) {
                        unsigned short hi, lo;
                        split_bf16(v, hi, lo);
                        Chi[off] = hi; Clo[off] = lo;
                    } else {
                        Chi[off] = f2bf(v);
                    }
                }
            }
        }
    }
}

// ---------------- edge attention: bf16 qkv [N][576], 4 nodes/block (wave each) --------
__global__ __launch_bounds__(256)
void attn_kernel(const unsigned short* __restrict__ qkv, const float* __restrict__ ea,
                 const float* __restrict__ We_l, const int2* __restrict__ csr2,
                 const int* __restrict__ row_ptr,
                 unsigned short* __restrict__ msg_hi, unsigned short* __restrict__ msg_lo) {
    __shared__ float sWe[4 * 192];
    const int tid = threadIdx.x;
    for (int i = tid; i < 768; i += 256) sWe[i] = We_l[i];
    __syncthreads();

    const int lane = tid & 63;
    const int node = blockIdx.x * 4 + (tid >> 6);
    const int d0 = (lane >> 4) * 48 + (lane & 15) * 3;
    const float scale = 0.14433756729740643f;  // 1/sqrt(48)
    size_t qb = (size_t)node * 576 + d0;
    float q0 = bf2f(qkv[qb]) * scale, q1 = bf2f(qkv[qb + 1]) * scale, q2 = bf2f(qkv[qb + 2]) * scale;
    float we0 = sWe[d0],     we1 = sWe[192 + d0],     we2 = sWe[384 + d0],     we3 = sWe[576 + d0];
    float wf0 = sWe[d0 + 1], wf1 = sWe[192 + d0 + 1], wf2 = sWe[384 + d0 + 1], wf3 = sWe[576 + d0 + 1];
    float wg0 = sWe[d0 + 2], wg1 = sWe[192 + d0 + 2], wg2 = sWe[384 + d0 + 2], wg3 = sWe[576 + d0 + 2];

    float m = -INFINITY, den = 0.f, a0 = 0.f, a1 = 0.f, a2 = 0.f;
    const int beg = row_ptr[node], end = row_ptr[node + 1];
    for (int p = beg; p < end; ++p) {
        int2 se = csr2[p];
        int s = se.x, e = se.y;
        const float4 w = *(const float4*)(ea + (size_t)e * 4);
        float e0 = w.x * we0 + w.y * we1 + w.z * we2 + w.w * we3;
        float e1 = w.x * wf0 + w.y * wf1 + w.z * wf2 + w.w * wf3;
        float e2 = w.x * wg0 + w.y * wg1 + w.z * wg2 + w.w * wg3;
        size_t kb = (size_t)s * 576 + 192 + d0;
        float ke0 = bf2f(qkv[kb])     + e0;
        float ke1 = bf2f(qkv[kb + 1]) + e1;
        float ke2 = bf2f(qkv[kb + 2]) + e2;
        float part = q0 * ke0 + q1 * ke1 + q2 * ke2;
        part += __shfl_xor(part, 1);
        part += __shfl_xor(part, 2);
        part += __shfl_xor(part, 4);
        part += __shfl_xor(part, 8);
        float logit = part;
        float mn = fmaxf(m, logit);
        float corr = __expf(m - mn);
        float pe = __expf(logit - mn);
        float ve0 = bf2f(qkv[kb + 192]) + e0;
        float ve1 = bf2f(qkv[kb + 193]) + e1;
        float ve2 = bf2f(qkv[kb + 194]) + e2;
        den = den * corr + pe;
        a0 = a0 * corr + pe * ve0;
        a1 = a1 * corr + pe * ve1;
        a2 = a2 * corr + pe * ve2;
        m = mn;
    }
    float inv = 1.f / (den + 1e-16f);
    size_t ob = (size_t)node * 192 + d0;
    unsigned short hi, lo;
    split_bf16(a0 * inv, hi, lo); msg_hi[ob] = hi;     msg_lo[ob] = lo;
    split_bf16(a1 * inv, hi, lo); msg_hi[ob + 1] = hi; msg_lo[ob + 1] = lo;
    split_bf16(a2 * inv, hi, lo); msg_hi[ob + 2] = hi; msg_lo[ob + 2] = lo;
}

// ---------------- edge head: bf16 gather -> MFMA (192->96) -> relu -> W3 --------------
__global__ __launch_bounds__(256)
void edge_head_kernel(const unsigned short* __restrict__ hsd, const float* __restrict__ ea,
                      const int* __restrict__ src, const int* __restrict__ dst,
                      const float* __restrict__ W1e, const float* __restrict__ b1,
                      const unsigned short* __restrict__ W2hi,
                      const float* __restrict__ b2, const float* __restrict__ W3,
                      const float* __restrict__ b3, float* __restrict__ out) {
    __shared__ __align__(16) unsigned short sZ[2][64][40];
    __shared__ __align__(16) unsigned short sW[96][40];
    __shared__ float sWe1[768];
    __shared__ float sB1[192];
    const int tid = threadIdx.x;
    const int wave = tid >> 6, lane = tid & 63;
    const int quad = lane >> 4, l16 = lane & 15;
    const int ebase = blockIdx.x * 64;

    for (int i = tid; i < 768; i += 256) sWe1[i] = W1e[i];
    if (tid < 192) sB1[tid] = b1[tid];

    const int el = tid >> 2, part = tid & 3;
    const int e = ebase + el;
    const int s = src[e], d = dst[e];
    const float4 eav = *(const float4*)(ea + (size_t)e * 4);
    const unsigned short* hs_p = hsd + (size_t)s * 384;
    const unsigned short* hd_p = hsd + (size_t)d * 384 + 192;

    floatx4 acc[6];
#pragma unroll
    for (int nt = 0; nt < 6; ++nt) acc[nt] = (floatx4)0.0f;
    __syncthreads();

    for (int kc = 0; kc < 192; kc += 32) {
        {
            int c0 = kc + part * 8;
            ushort8 hsv = *(const ushort8*)(hs_p + c0);
            ushort8 hdv = *(const ushort8*)(hd_p + c0);
            ushort8 hv, lv;
#pragma unroll
            for (int j = 0; j < 8; ++j) {
                int c = c0 + j;
                float ce = sB1[c] + eav.x * sWe1[c] + eav.y * sWe1[192 + c]
                         + eav.z * sWe1[384 + c] + eav.w * sWe1[576 + c];
                float v = fmaxf(bf2f(hsv[j]) + bf2f(hdv[j]) + ce, 0.f);
                unsigned short hi, lo;
                split_bf16(v, hi, lo);
                hv[j] = hi; lv[j] = lo;
            }
            *(ushort8*)&sZ[0][el][part * 8] = hv;
            *(ushort8*)&sZ[1][el][part * 8] = lv;
        }
        // stage W2hi chunk: 96 rows * 4 quads = 384 uint4
#pragma unroll
        for (int it = 0; it < 2; ++it) {
            int i = it * 256 + tid;
            if (i < 384) {
                int n = i >> 2, qq = i & 3;
                *(uint4*)&sW[n][qq * 8] = *(const uint4*)(W2hi + (size_t)n * 192 + kc + qq * 8);
            }
        }
        __syncthreads();
        short8 zh = *(const short8*)&sZ[0][wave * 16 + l16][quad * 8];
        short8 zl = *(const short8*)&sZ[1][wave * 16 + l16][quad * 8];
#pragma unroll
        for (int nt = 0; nt < 6; ++nt) {
            short8 bh = *(const short8*)&sW[nt * 16 + l16][quad * 8];
            acc[nt] = mfma16(zh, bh, acc[nt]);
            acc[nt] = mfma16(zl, bh, acc[nt]);
        }
        __syncthreads();
    }

    float w3[6], bb2[6];
#pragma unroll
    for (int nt = 0; nt < 6; ++nt) {
        int col = nt * 16 + l16;
        w3[nt] = W3[col];
        bb2[nt] = b2[col];
    }
    float b3v = b3[0];
#pragma unroll
    for (int reg = 0; reg < 4; ++reg) {
        float sacc = 0.f;
#pragma unroll
        for (int nt = 0; nt < 6; ++nt) {
            float z = fmaxf(acc[nt][reg] + bb2[nt], 0.f);
            sacc = fmaf(z, w3[nt], sacc);
        }
#pragma unroll
        for (int off = 1; off < 16; off <<= 1) sacc += __shfl_xor(sacc, off);
        if (l16 == 0) out[ebase + wave * 16 + quad * 4 + reg] = sacc + b3v;
    }
}

extern "C" void kernel_launch(void* const* d_in, const int* in_sizes, int n_in,
                              void* d_out, int out_size, void* d_ws, size_t ws_size,
                              hipStream_t stream) {
    const float* x     = (const float*)d_in[0];
    const int*   eidx  = (const int*)d_in[1];
    const float* ea    = (const float*)d_in[2];
    const int*   batch = (const int*)d_in[3];
    const int*   gptr  = (const int*)d_in[4];
    const int*   tgid  = (const int*)d_in[5];
    const float* gp    = (const float*)d_in[6];
    const float* sp    = (const float*)d_in[7];
    const float* epp   = (const float*)d_in[8];
    const float* W_in  = (const float*)d_in[9];
    const float* b_in  = (const float*)d_in[10];
    const float* Wq    = (const float*)d_in[11];
    const float* Wk    = (const float*)d_in[12];
    const float* Wv    = (const float*)d_in[13];
    const float* We    = (const float*)d_in[14];
    const float* Wo    = (const float*)d_in[15];
    const float* bo    = (const float*)d_in[16];
    const float* ln1g  = (const float*)d_in[17];
    const float* ln1b  = (const float*)d_in[18];
    const float* Wf1   = (const float*)d_in[19];
    const float* bf1   = (const float*)d_in[20];
    const float* Wf2   = (const float*)d_in[21];
    const float* bf2   = (const float*)d_in[22];
    const float* ln2g  = (const float*)d_in[23];
    const float* ln2b  = (const float*)d_in[24];
    const float* We1   = (const float*)d_in[25];
    const float* be1   = (const float*)d_in[26];
    const float* We2   = (const float*)d_in[27];
    const float* be2   = (const float*)d_in[28];
    const float* We3   = (const float*)d_in[29];
    const float* be3   = (const float*)d_in[30];
    const int* src = eidx;
    const int* dst = eidx + N_EDGES;

    unsigned short* ub = (unsigned short*)d_ws;
    unsigned short* featH = ub;                  // 40000*32
    unsigned short* featL = ub + 1280000;
    unsigned short* hH    = ub + 2560000;        // 40000*192
    unsigned short* hL    = ub + 10240000;
    unsigned short* htH   = ub + 17920000;
    unsigned short* htL   = ub + 25600000;
    unsigned short* msgH  = ub + 33280000;
    unsigned short* msgL  = ub + 40960000;
    unsigned short* rbuf  = ub + 48640000;       // 40000*768 region: qkv | ffH/ffL | hsd
    unsigned short* qkvB  = rbuf;                // 40000*576
    unsigned short* ffH   = rbuf;                // 40000*384
    unsigned short* ffL   = rbuf + 15360000;
    unsigned short* hsdB  = rbuf;                // 40000*384
    unsigned short* wb    = ub + 79360000;       // WTOT
    int* ib   = (int*)(ub + 80343040);
    int* cnt  = ib;
    int* rowp = ib + 40000;
    int* curs = ib + 80004;
    int2* csr2 = (int2*)(ib + 120004);
    int* bsum  = ib + 920004;
    int* boffs = ib + 920044;

    hipMemsetAsync(cnt, 0, N_NODES * sizeof(int), stream);
    count_kernel<<<1563, 256, 0, stream>>>(dst, cnt, N_EDGES);
    scan1_kernel<<<40, 1024, 0, stream>>>(cnt, rowp, bsum, N_NODES);
    scan2_kernel<<<1, 64, 0, stream>>>(bsum, boffs, rowp, 40, N_NODES);
    scan3_kernel<<<40, 1024, 0, stream>>>(rowp, curs, boffs, N_NODES);
    scatter_kernel<<<1563, 256, 0, stream>>>(src, dst, curs, csr2, N_EDGES);
    feat_kernel<<<5000, 256, 0, stream>>>(x, batch, gptr, tgid, gp, sp, epp, featH, featL, N_NODES);
    prep_kernel<<<3840, 256, 0, stream>>>(W_in, Wq, Wk, Wv, Wo, Wf1, Wf2, We1, We2, wb);

    dim3 blk(256);
    // input projection: feat[40000,32 planes] @ W_in -> h planes
    mfma_gemm<0, 1><<<dim3(313, 1), blk, 0, stream>>>(featH, featL, N_NODES, 32,
        wb + WOFF_WIN, b_in, nullptr, nullptr, nullptr, nullptr, hH, hL, 192);

    for (int l = 0; l < 3; ++l) {
        mfma_gemm<0, 0><<<dim3(313, 3), blk, 0, stream>>>(hH, hL, N_NODES, 192,
            wb + WOFF_QKV + l * 110592, nullptr, nullptr, nullptr, nullptr, nullptr,
            qkvB, nullptr, 576);
        attn_kernel<<<10000, 256, 0, stream>>>(qkvB, ea, We + l * 768, csr2, rowp, msgH, msgL);
        mfma_gemm<2, 1><<<dim3(313, 1), blk, 0, stream>>>(msgH, msgL, N_NODES, 192,
            wb + WOFF_WO + l * 36864, bo + l * 192, hH, hL, ln1g + l * 192, ln1b + l * 192,
            htH, htL, 192);
        mfma_gemm<1, 1><<<dim3(313, 2), blk, 0, stream>>>(htH, htL, N_NODES, 192,
            wb + WOFF_WF1 + l * 73728, bf1 + l * 384, nullptr, nullptr, nullptr, nullptr,
            ffH, ffL, 384);
        mfma_gemm<2, 1><<<dim3(313, 1), blk, 0, stream>>>(ffH, ffL, N_NODES, 384,
            wb + WOFF_WF2 + l * 73728, bf2 + l * 192, htH, htL, ln2g + l * 192, ln2b + l * 192,
            hH, hL, 192);
    }

    // edge head pre-projections: [Hs|Hd] = h @ [We1[0:192] | We1[192:384]] -> bf16 single
    mfma_gemm<0, 0><<<dim3(313, 2), blk, 0, stream>>>(hH, hL, N_NODES, 192,
        wb + WOFF_HSD, nullptr, nullptr, nullptr, nullptr, nullptr, hsdB, nullptr, 384);
    edge_head_kernel<<<6250, blk, 0, stream>>>(hsdB, ea, src, dst,
        We1 + 384 * 192, be1, wb + WOFF_WE2, be2, We3, be3, (float*)d_out);
}

// Round 4
// 1006.618 us; speedup vs baseline: 1.1997x; 1.1997x over previous
//
#include <hip/hip_runtime.h>
#include <hip/hip_bf16.h>
#include <math.h>

#define N_NODES 40000
#define N_EDGES 400000
#define GCLIP 511

using short8  = __attribute__((ext_vector_type(8))) short;
using ushort8 = __attribute__((ext_vector_type(8))) unsigned short;
using floatx4 = __attribute__((ext_vector_type(4))) float;

__device__ __forceinline__ void split_bf16(float v, unsigned short& hi, unsigned short& lo) {
    __hip_bfloat16 h = __float2bfloat16(v);
    float r = v - __bfloat162float(h);
    __hip_bfloat16 l = __float2bfloat16(r);
    hi = *(unsigned short*)&h;
    lo = *(unsigned short*)&l;
}
__device__ __forceinline__ unsigned short f2bf(float f) {
    __hip_bfloat16 h = __float2bfloat16(f);
    return *(unsigned short*)&h;
}
__device__ __forceinline__ float bf2f(unsigned short u) {
    __hip_bfloat16 h = *(__hip_bfloat16*)&u;
    return __bfloat162float(h);
}
__device__ __forceinline__ floatx4 mfma16(short8 a, short8 b, floatx4 c) {
    return __builtin_amdgcn_mfma_f32_16x16x32_bf16(a, b, c, 0, 0, 0);
}

// ---------------- CSR build ----------------
__global__ void count_kernel(const int* __restrict__ dst, int* __restrict__ cnt, int E) {
    int e = blockIdx.x * 256 + threadIdx.x;
    if (e < E) atomicAdd(&cnt[dst[e]], 1);
}

__global__ void scan1_kernel(const int* __restrict__ cnt, int* __restrict__ rowp,
                             int* __restrict__ bsum, int n) {
    __shared__ int wsum[16];
    __shared__ int woff[16];
    int tid = threadIdx.x, wave = tid >> 6, lane = tid & 63;
    int i = blockIdx.x * 1024 + tid;
    int v = (i < n) ? cnt[i] : 0;
    int x = v;
    for (int off = 1; off < 64; off <<= 1) {
        int t = __shfl_up(x, off);
        if (lane >= off) x += t;
    }
    if (lane == 63) wsum[wave] = x;
    __syncthreads();
    if (wave == 0 && lane < 16) {
        int s = wsum[lane];
        for (int off = 1; off < 16; off <<= 1) {
            int t = __shfl_up(s, off);
            if (lane >= off) s += t;
        }
        woff[lane] = s;
    }
    __syncthreads();
    int incl = x + ((wave == 0) ? 0 : woff[wave - 1]);
    if (i < n) rowp[i] = incl - v;
    if (tid == 1023) bsum[blockIdx.x] = incl;
}

__global__ void scan2_kernel(const int* __restrict__ bsum, int* __restrict__ boffs,
                             int* __restrict__ rowp, int nb, int n) {
    int lane = threadIdx.x;
    int v = (lane < nb) ? bsum[lane] : 0;
    int x = v;
    for (int off = 1; off < 64; off <<= 1) {
        int t = __shfl_up(x, off);
        if (lane >= off) x += t;
    }
    if (lane < nb) boffs[lane] = x - v;
    if (lane == nb - 1) rowp[n] = x;
}

__global__ void scan3_kernel(int* __restrict__ rowp, int* __restrict__ curs,
                             const int* __restrict__ boffs, int n) {
    int i = blockIdx.x * 1024 + threadIdx.x;
    if (i < n) {
        int v = rowp[i] + boffs[blockIdx.x];
        rowp[i] = v;
        curs[i] = v;
    }
}

__global__ void scatter_kernel(const int* __restrict__ src, const int* __restrict__ dst,
                               int* __restrict__ cursor, int2* __restrict__ csr2, int E) {
    int e = blockIdx.x * 256 + threadIdx.x;
    if (e < E) {
        int pos = atomicAdd(&cursor[dst[e]], 1);
        csr2[pos] = make_int2(src[e], e);
    }
}

// ---------------- feature build -> bf16 hi/lo planes [N][32] (cols 16..31 zero) -------
__global__ void feat_kernel(const float* __restrict__ x, const int* __restrict__ batch,
                            const int* __restrict__ gptr, const int* __restrict__ tgid,
                            const float* __restrict__ gp, const float* __restrict__ sp,
                            const float* __restrict__ ep,
                            unsigned short* __restrict__ fhi, unsigned short* __restrict__ flo,
                            int n) {
    int idx = blockIdx.x * 256 + threadIdx.x;
    if (idx >= n * 32) return;
    int node = idx >> 5, c = idx & 31;
    float v = 0.f;
    if (c < 4) {
        v = x[node * 4 + c];
    } else if (c < 7) {
        int gid = gptr[batch[node]] + tgid[node];
        gid = min(max(gid, 0), GCLIP);
        v = gp[gid * 3 + (c - 4)];
    } else if (c < 10) {
        v = sp[node * 3 + (c - 7)];
    } else if (c < 16) {
        int gid = gptr[batch[node]] + tgid[node];
        gid = min(max(gid, 0), GCLIP);
        v = ep[gid * 6 + (c - 10)];
    }
    unsigned short hi, lo;
    split_bf16(v, hi, lo);
    fhi[idx] = hi;
    flo[idx] = lo;
}

// ---------------- weight prep: transpose to [Nrows][Ka] bf16 (hi only) ----------------
#define WOFF_WIN 0
#define WOFF_QKV 6144
#define WOFF_WO  337920
#define WOFF_WF1 448512
#define WOFF_WF2 669696
#define WOFF_HSD 890880
#define WOFF_WE2 964608
#define WTOT     983040

__global__ void prep_kernel(const float* __restrict__ W_in, const float* __restrict__ Wq,
                            const float* __restrict__ Wk, const float* __restrict__ Wv,
                            const float* __restrict__ Wo, const float* __restrict__ Wf1,
                            const float* __restrict__ Wf2, const float* __restrict__ We1,
                            const float* __restrict__ We2, unsigned short* __restrict__ wb) {
    int idx = blockIdx.x * 256 + threadIdx.x;
    if (idx >= WTOT) return;
    float val;
    if (idx < WOFF_QKV) {                       // W_in^T [192][32], K=16 padded
        int n = idx / 32, k = idx % 32;
        val = (k < 16) ? W_in[k * 192 + n] : 0.f;
    } else if (idx < WOFF_WO) {                 // Wqkv^T [576][192] x3; q rows pre-scaled
        int r = idx - WOFF_QKV; int l = r / 110592; r %= 110592;
        int n = r / 192, k = r % 192;
        const float* s = (n < 192) ? Wq : (n < 384 ? Wk : Wv);
        val = s[l * 36864 + k * 192 + (n % 192)];
        if (n < 192) val *= 0.14433756729740643f;   // 1/sqrt(48) folded into Wq
    } else if (idx < WOFF_WF1) {                // Wo^T [192][192] x3
        int r = idx - WOFF_WO; int l = r / 36864; r %= 36864;
        int n = r / 192, k = r % 192;
        val = Wo[l * 36864 + k * 192 + n];
    } else if (idx < WOFF_WF2) {                // Wf1^T [384][192] x3
        int r = idx - WOFF_WF1; int l = r / 73728; r %= 73728;
        int n = r / 192, k = r % 192;
        val = Wf1[l * 73728 + k * 384 + n];
    } else if (idx < WOFF_HSD) {                // Wf2^T [192][384] x3
        int r = idx - WOFF_WF2; int l = r / 73728; r %= 73728;
        int n = r / 384, k = r % 384;
        val = Wf2[l * 73728 + k * 192 + n];
    } else if (idx < WOFF_WE2) {                // [Hs|Hd]^T [384][192]
        int r = idx - WOFF_HSD;
        int n = r / 192, k = r % 192;
        val = (n < 192) ? We1[k * 192 + n] : We1[(192 + k) * 192 + (n - 192)];
    } else {                                    // We2^T [96][192]
        int r = idx - WOFF_WE2;
        int n = r / 192, k = r % 192;
        val = We2[k * 96 + n];
    }
    wb[idx] = f2bf(val);
}

// ---------------- MFMA GEMM: A global bf16 hi/lo planes, B staged in LDS --------------
// BM=128 (4 waves x 32 rows), BN columns/block, K staged in KCH chunks.
// EPI: 0 none, 1 relu, 2 bias+resid+LN (BN=192, grid.y=1). DUAL: write hi/lo planes.
// Output index: row*oldc + (cbase+col)*cmul + cadd.
template <int EPI, int DUAL, int BN, int KCH>
__global__ __launch_bounds__(256, 2)
void mfma_gemm(const unsigned short* __restrict__ Ahi, const unsigned short* __restrict__ Alo,
               int M, int Ka,
               const unsigned short* __restrict__ B, const float* __restrict__ bias,
               const unsigned short* __restrict__ Rhi, const unsigned short* __restrict__ Rlo,
               const float* __restrict__ lng, const float* __restrict__ lnb,
               unsigned short* __restrict__ Chi, unsigned short* __restrict__ Clo,
               int oldc, int cmul, int cadd) {
    constexpr int NT = BN / 16;
    __shared__ __align__(16) unsigned short sB[BN][KCH + 8];
    const int tid = threadIdx.x;
    const int wave = tid >> 6, lane = tid & 63;
    const int quad = lane >> 4, l16 = lane & 15;
    const int rbase = blockIdx.x * 128;
    const int cbase = blockIdx.y * BN;

    floatx4 acc[2][NT];
#pragma unroll
    for (int mt = 0; mt < 2; ++mt)
#pragma unroll
        for (int nt = 0; nt < NT; ++nt) acc[mt][nt] = (floatx4)0.0f;

    const int r0 = min(rbase + wave * 32 + l16, M - 1);
    const int r1 = min(rbase + wave * 32 + 16 + l16, M - 1);
    const unsigned short* pa0h = Ahi + (size_t)r0 * Ka + quad * 8;
    const unsigned short* pa0l = Alo + (size_t)r0 * Ka + quad * 8;
    const unsigned short* pa1h = Ahi + (size_t)r1 * Ka + quad * 8;
    const unsigned short* pa1l = Alo + (size_t)r1 * Ka + quad * 8;

    for (int kb = 0; kb < Ka; kb += KCH) {
        // stage B chunk [BN][KCH] via b128
        for (int i = tid * 8; i < BN * KCH; i += 2048) {
            int n = i / KCH, kk = i % KCH;
            *(uint4*)&sB[n][kk] = *(const uint4*)(B + (size_t)(cbase + n) * Ka + kb + kk);
        }
        __syncthreads();
#pragma unroll
        for (int kc = 0; kc < KCH; kc += 32) {
            const int kg = kb + kc;
            short8 ah0 = *(const short8*)(pa0h + kg);
            short8 al0 = *(const short8*)(pa0l + kg);
            short8 ah1 = *(const short8*)(pa1h + kg);
            short8 al1 = *(const short8*)(pa1l + kg);
#pragma unroll
            for (int nt = 0; nt < NT; ++nt) {
                short8 b = *(const short8*)&sB[nt * 16 + l16][kc + quad * 8];
                acc[0][nt] = mfma16(ah0, b, acc[0][nt]);
                acc[0][nt] = mfma16(al0, b, acc[0][nt]);
                acc[1][nt] = mfma16(ah1, b, acc[1][nt]);
                acc[1][nt] = mfma16(al1, b, acc[1][nt]);
            }
        }
        if (kb + KCH < Ka) __syncthreads();
    }

    float bb[NT], gg[NT], be[NT];
#pragma unroll
    for (int nt = 0; nt < NT; ++nt) {
        int colg = cbase + nt * 16 + l16;
        bb[nt] = bias ? bias[colg] : 0.f;
        if (EPI == 2) { gg[nt] = lng[colg]; be[nt] = lnb[colg]; }
    }
#pragma unroll
    for (int mt = 0; mt < 2; ++mt) {
#pragma unroll
        for (int reg = 0; reg < 4; ++reg) {
            int row = rbase + wave * 32 + mt * 16 + quad * 4 + reg;
            if (EPI == 2) {
                int rr = min(row, M - 1);
                float v[NT], s = 0.f, q = 0.f;
#pragma unroll
                for (int nt = 0; nt < NT; ++nt) {
                    size_t off = (size_t)rr * 192 + nt * 16 + l16;
                    float resid = bf2f(Rhi[off]) + bf2f(Rlo[off]);
                    v[nt] = acc[mt][nt][reg] + bb[nt] + resid;
                    s += v[nt]; q += v[nt] * v[nt];
                }
#pragma unroll
                for (int off = 1; off < 16; off <<= 1) {
                    s += __shfl_xor(s, off);
                    q += __shfl_xor(q, off);
                }
                float mean = s * (1.f / 192.f);
                float var = q * (1.f / 192.f) - mean * mean;
                float rs = rsqrtf(var + 1e-5f);
                if (row < M) {
#pragma unroll
                    for (int nt = 0; nt < NT; ++nt) {
                        float r = (v[nt] - mean) * rs * gg[nt] + be[nt];
                        unsigned short hi, lo;
                        split_bf16(r, hi, lo);
                        size_t off = (size_t)row * 192 + nt * 16 + l16;
                        Chi[off] = hi; Clo[off] = lo;
                    }
                }
            } else if (row < M) {
#pragma unroll
                for (int nt = 0; nt < NT; ++nt) {
                    float v = acc[mt][nt][reg] + bb[nt];
                    if (EPI == 1) v = fmaxf(v, 0.f);
                    size_t off = (size_t)row * oldc + (size_t)(cbase + nt * 16 + l16) * cmul + cadd;
                    if (DUAL) {
                        unsigned short hi, lo;
                        split_bf16(v, hi, lo);
                        Chi[off] = hi; Clo[off] = lo;
                    } else {
                        Chi[off] = f2bf(v);
                    }
                }
            }
        }
    }
}

// ---------------- edge attention: q bf16 [N][192] (pre-scaled), kv interleaved --------
// logit = q.k[s] + qe.w_e ; msg = (sum p*v + (sum p*w_e)@We)/den  (exact factoring)
__global__ __launch_bounds__(256)
void attn_kernel(const unsigned short* __restrict__ qB, const unsigned short* __restrict__ kvB,
                 const float* __restrict__ ea, const float* __restrict__ We_l,
                 const int2* __restrict__ csr2, const int* __restrict__ row_ptr,
                 unsigned short* __restrict__ msg_hi, unsigned short* __restrict__ msg_lo) {
    __shared__ float sWe[768];
    const int tid = threadIdx.x;
    for (int i = tid; i < 768; i += 256) sWe[i] = We_l[i];
    __syncthreads();

    const int lane = tid & 63;
    const int node = blockIdx.x * 4 + (tid >> 6);
    const int d0 = (lane >> 4) * 48 + (lane & 15) * 3;

    float W[4][3];
#pragma unroll
    for (int w = 0; w < 4; ++w) {
        W[w][0] = sWe[w * 192 + d0];
        W[w][1] = sWe[w * 192 + d0 + 1];
        W[w][2] = sWe[w * 192 + d0 + 2];
    }
    size_t qoff = (size_t)node * 192 + d0;
    float q0 = bf2f(qB[qoff]), q1 = bf2f(qB[qoff + 1]), q2 = bf2f(qB[qoff + 2]);
    // qe[w] = q . We[w], reduced over the 16-lane head group
    float qe0 = q0 * W[0][0] + q1 * W[0][1] + q2 * W[0][2];
    float qe1 = q0 * W[1][0] + q1 * W[1][1] + q2 * W[1][2];
    float qe2 = q0 * W[2][0] + q1 * W[2][1] + q2 * W[2][2];
    float qe3 = q0 * W[3][0] + q1 * W[3][1] + q2 * W[3][2];
#pragma unroll
    for (int off = 1; off < 16; off <<= 1) {
        qe0 += __shfl_xor(qe0, off);
        qe1 += __shfl_xor(qe1, off);
        qe2 += __shfl_xor(qe2, off);
        qe3 += __shfl_xor(qe3, off);
    }

    const unsigned int* kv = (const unsigned int*)kvB;
    const float4* ea4 = (const float4*)ea;

    float m = -INFINITY, den = 0.f;
    float v0 = 0.f, v1 = 0.f, v2 = 0.f;
    float wa0 = 0.f, wa1 = 0.f, wa2 = 0.f, wa3 = 0.f;
    const int beg = row_ptr[node], end = row_ptr[node + 1];
    int p = beg;
    for (; p + 1 < end; p += 2) {
        int2 se1 = csr2[p], se2 = csr2[p + 1];
        size_t b1 = (size_t)se1.x * 192 + d0;
        size_t b2 = (size_t)se2.x * 192 + d0;
        unsigned int u10 = kv[b1], u11 = kv[b1 + 1], u12 = kv[b1 + 2];
        unsigned int u20 = kv[b2], u21 = kv[b2 + 1], u22 = kv[b2 + 2];
        float4 w1 = ea4[se1.y];
        float4 w2 = ea4[se2.y];
        float d1 = q0 * bf2f((unsigned short)u10) + q1 * bf2f((unsigned short)u11)
                 + q2 * bf2f((unsigned short)u12);
        float d2 = q0 * bf2f((unsigned short)u20) + q1 * bf2f((unsigned short)u21)
                 + q2 * bf2f((unsigned short)u22);
#pragma unroll
        for (int off = 1; off < 16; off <<= 1) {
            d1 += __shfl_xor(d1, off);
            d2 += __shfl_xor(d2, off);
        }
        float l1 = d1 + w1.x * qe0 + w1.y * qe1 + w1.z * qe2 + w1.w * qe3;
        float l2 = d2 + w2.x * qe0 + w2.y * qe1 + w2.z * qe2 + w2.w * qe3;
        float mn = fmaxf(m, fmaxf(l1, l2));
        float corr = __expf(m - mn);
        float p1 = __expf(l1 - mn);
        float p2 = __expf(l2 - mn);
        den = den * corr + p1 + p2;
        v0 = v0 * corr + p1 * bf2f((unsigned short)(u10 >> 16)) + p2 * bf2f((unsigned short)(u20 >> 16));
        v1 = v1 * corr + p1 * bf2f((unsigned short)(u11 >> 16)) + p2 * bf2f((unsigned short)(u21 >> 16));
        v2 = v2 * corr + p1 * bf2f((unsigned short)(u12 >> 16)) + p2 * bf2f((unsigned short)(u22 >> 16));
        wa0 = wa0 * corr + p1 * w1.x + p2 * w2.x;
        wa1 = wa1 * corr + p1 * w1.y + p2 * w2.y;
        wa2 = wa2 * corr + p1 * w1.z + p2 * w2.z;
        wa3 = wa3 * corr + p1 * w1.w + p2 * w2.w;
        m = mn;
    }
    if (p < end) {
        int2 se = csr2[p];
        size_t b = (size_t)se.x * 192 + d0;
        unsigned int u0 = kv[b], u1 = kv[b + 1], u2 = kv[b + 2];
        float4 w = ea4[se.y];
        float d = q0 * bf2f((unsigned short)u0) + q1 * bf2f((unsigned short)u1)
                + q2 * bf2f((unsigned short)u2);
#pragma unroll
        for (int off = 1; off < 16; off <<= 1) d += __shfl_xor(d, off);
        float l = d + w.x * qe0 + w.y * qe1 + w.z * qe2 + w.w * qe3;
        float mn = fmaxf(m, l);
        float corr = __expf(m - mn);
        float pe = __expf(l - mn);
        den = den * corr + pe;
        v0 = v0 * corr + pe * bf2f((unsigned short)(u0 >> 16));
        v1 = v1 * corr + pe * bf2f((unsigned short)(u1 >> 16));
        v2 = v2 * corr + pe * bf2f((unsigned short)(u2 >> 16));
        wa0 = wa0 * corr + pe * w.x;
        wa1 = wa1 * corr + pe * w.y;
        wa2 = wa2 * corr + pe * w.z;
        wa3 = wa3 * corr + pe * w.w;
    }
    float inv = 1.f / (den + 1e-16f);
    float m0 = (v0 + wa0 * W[0][0] + wa1 * W[1][0] + wa2 * W[2][0] + wa3 * W[3][0]) * inv;
    float m1 = (v1 + wa0 * W[0][1] + wa1 * W[1][1] + wa2 * W[2][1] + wa3 * W[3][1]) * inv;
    float m2 = (v2 + wa0 * W[0][2] + wa1 * W[1][2] + wa2 * W[2][2] + wa3 * W[3][2]) * inv;
    size_t ob = (size_t)node * 192 + d0;
    unsigned short hi, lo;
    split_bf16(m0, hi, lo); msg_hi[ob] = hi;     msg_lo[ob] = lo;
    split_bf16(m1, hi, lo); msg_hi[ob + 1] = hi; msg_lo[ob + 1] = lo;
    split_bf16(m2, hi, lo); msg_hi[ob + 2] = hi; msg_lo[ob + 2] = lo;
}

// ---------------- edge head: bf16 gather -> MFMA (192->96) -> relu -> W3 --------------
// W2 staged once; K-loop barrier-free (sZ traffic is wave-local).
__global__ __launch_bounds__(256)
void edge_head_kernel(const unsigned short* __restrict__ hsd, const float* __restrict__ ea,
                      const int* __restrict__ src, const int* __restrict__ dst,
                      const float* __restrict__ W1e, const float* __restrict__ b1,
                      const unsigned short* __restrict__ W2hi,
                      const float* __restrict__ b2, const float* __restrict__ W3,
                      const float* __restrict__ b3, float* __restrict__ out) {
    __shared__ __align__(16) unsigned short sZ[2][64][40];
    __shared__ __align__(16) unsigned short sW[96][200];
    __shared__ float sWe1[768];
    __shared__ float sB1[192];
    const int tid = threadIdx.x;
    const int wave = tid >> 6, lane = tid & 63;
    const int quad = lane >> 4, l16 = lane & 15;
    const int ebase = blockIdx.x * 64;

    for (int i = tid; i < 768; i += 256) sWe1[i] = W1e[i];
    if (tid < 192) sB1[tid] = b1[tid];
    for (int i = tid * 8; i < 96 * 192; i += 2048) {
        int n = i / 192, kk = i % 192;
        *(uint4*)&sW[n][kk] = *(const uint4*)(W2hi + (size_t)n * 192 + kk);
    }

    const int el = tid >> 2, part = tid & 3;
    const int e = ebase + el;
    const int s = src[e], d = dst[e];
    const float4 eav = *(const float4*)(ea + (size_t)e * 4);
    const unsigned short* hs_p = hsd + (size_t)s * 384;
    const unsigned short* hd_p = hsd + (size_t)d * 384 + 192;

    floatx4 acc[6];
#pragma unroll
    for (int nt = 0; nt < 6; ++nt) acc[nt] = (floatx4)0.0f;
    __syncthreads();

    for (int kc = 0; kc < 192; kc += 32) {
        {
            int c0 = kc + part * 8;
            ushort8 hsv = *(const ushort8*)(hs_p + c0);
            ushort8 hdv = *(const ushort8*)(hd_p + c0);
            ushort8 hv, lv;
#pragma unroll
            for (int j = 0; j < 8; ++j) {
                int c = c0 + j;
                float ce = sB1[c] + eav.x * sWe1[c] + eav.y * sWe1[192 + c]
                         + eav.z * sWe1[384 + c] + eav.w * sWe1[576 + c];
                float v = fmaxf(bf2f(hsv[j]) + bf2f(hdv[j]) + ce, 0.f);
                unsigned short hi, lo;
                split_bf16(v, hi, lo);
                hv[j] = hi; lv[j] = lo;
            }
            *(ushort8*)&sZ[0][el][part * 8] = hv;
            *(ushort8*)&sZ[1][el][part * 8] = lv;
        }
        // wave-local: writers and readers of sZ rows [wave*16, wave*16+16) are the same
        // wave; same-wave DS ops complete in order -> no __syncthreads needed.
        short8 zh = *(const short8*)&sZ[0][wave * 16 + l16][quad * 8];
        short8 zl = *(const short8*)&sZ[1][wave * 16 + l16][quad * 8];
#pragma unroll
        for (int nt = 0; nt < 6; ++nt) {
            short8 bh = *(const short8*)&sW[nt * 16 + l16][kc + quad * 8];
            acc[nt] = mfma16(zh, bh, acc[nt]);
            acc[nt] = mfma16(zl, bh, acc[nt]);
        }
    }

    float w3[6], bb2[6];
#pragma unroll
    for (int nt = 0; nt < 6; ++nt) {
        int col = nt * 16 + l16;
        w3[nt] = W3[col];
        bb2[nt] = b2[col];
    }
    float b3v = b3[0];
#pragma unroll
    for (int reg = 0; reg < 4; ++reg) {
        float sacc = 0.f;
#pragma unroll
        for (int nt = 0; nt < 6; ++nt) {
            float z = fmaxf(acc[nt][reg] + bb2[nt], 0.f);
            sacc = fmaf(z, w3[nt], sacc);
        }
#pragma unroll
        for (int off = 1; off < 16; off <<= 1) sacc += __shfl_xor(sacc, off);
        if (l16 == 0) out[ebase + wave * 16 + quad * 4 + reg] = sacc + b3v;
    }
}

extern "C" void kernel_launch(void* const* d_in, const int* in_sizes, int n_in,
                              void* d_out, int out_size, void* d_ws, size_t ws_size,
                              hipStream_t stream) {
    const float* x     = (const float*)d_in[0];
    const int*   eidx  = (const int*)d_in[1];
    const float* ea    = (const float*)d_in[2];
    const int*   batch = (const int*)d_in[3];
    const int*   gptr  = (const int*)d_in[4];
    const int*   tgid  = (const int*)d_in[5];
    const float* gp    = (const float*)d_in[6];
    const float* sp    = (const float*)d_in[7];
    const float* epp   = (const float*)d_in[8];
    const float* W_in  = (const float*)d_in[9];
    const float* b_in  = (const float*)d_in[10];
    const float* Wq    = (const float*)d_in[11];
    const float* Wk    = (const float*)d_in[12];
    const float* Wv    = (const float*)d_in[13];
    const float* We    = (const float*)d_in[14];
    const float* Wo    = (const float*)d_in[15];
    const float* bo    = (const float*)d_in[16];
    const float* ln1g  = (const float*)d_in[17];
    const float* ln1b  = (const float*)d_in[18];
    const float* Wf1   = (const float*)d_in[19];
    const float* bf1   = (const float*)d_in[20];
    const float* Wf2   = (const float*)d_in[21];
    const float* bf2   = (const float*)d_in[22];
    const float* ln2g  = (const float*)d_in[23];
    const float* ln2b  = (const float*)d_in[24];
    const float* We1   = (const float*)d_in[25];
    const float* be1   = (const float*)d_in[26];
    const float* We2   = (const float*)d_in[27];
    const float* be2   = (const float*)d_in[28];
    const float* We3   = (const float*)d_in[29];
    const float* be3   = (const float*)d_in[30];
    const int* src = eidx;
    const int* dst = eidx + N_EDGES;

    unsigned short* ub = (unsigned short*)d_ws;
    unsigned short* featH = ub;                  // 40000*32
    unsigned short* featL = ub + 1280000;
    unsigned short* hH    = ub + 2560000;        // 40000*192 each
    unsigned short* hL    = ub + 10240000;
    unsigned short* htH   = ub + 17920000;
    unsigned short* htL   = ub + 25600000;
    unsigned short* msgH  = ub + 33280000;
    unsigned short* msgL  = ub + 40960000;
    unsigned short* rbuf  = ub + 48640000;       // 40000*768 region
    unsigned short* qB    = rbuf;                // 40000*192
    unsigned short* kvB   = rbuf + 7680000;      // 40000*384 interleaved k/v
    unsigned short* ffH   = rbuf;                // 40000*384 (after attn)
    unsigned short* ffL   = rbuf + 15360000;
    unsigned short* hsdB  = rbuf;                // 40000*384
    unsigned short* wb    = ub + 79360000;       // WTOT
    int* ib   = (int*)(ub + 80343040);
    int* cnt  = ib;
    int* rowp = ib + 40000;
    int* curs = ib + 80004;
    int2* csr2 = (int2*)(ib + 120004);
    int* bsum  = ib + 920004;
    int* boffs = ib + 920044;

    hipMemsetAsync(cnt, 0, N_NODES * sizeof(int), stream);
    count_kernel<<<1563, 256, 0, stream>>>(dst, cnt, N_EDGES);
    scan1_kernel<<<40, 1024, 0, stream>>>(cnt, rowp, bsum, N_NODES);
    scan2_kernel<<<1, 64, 0, stream>>>(bsum, boffs, rowp, 40, N_NODES);
    scan3_kernel<<<40, 1024, 0, stream>>>(rowp, curs, boffs, N_NODES);
    scatter_kernel<<<1563, 256, 0, stream>>>(src, dst, curs, csr2, N_EDGES);
    feat_kernel<<<5000, 256, 0, stream>>>(x, batch, gptr, tgid, gp, sp, epp, featH, featL, N_NODES);
    prep_kernel<<<3840, 256, 0, stream>>>(W_in, Wq, Wk, Wv, Wo, Wf1, Wf2, We1, We2, wb);

    dim3 blk(256);
    // input projection: feat[40000, K=32 planes] @ W_in -> h planes
    mfma_gemm<0, 1, 96, 32><<<dim3(313, 2), blk, 0, stream>>>(featH, featL, N_NODES, 32,
        wb + WOFF_WIN, b_in, nullptr, nullptr, nullptr, nullptr, hH, hL, 192, 1, 0);

    for (int l = 0; l < 3; ++l) {
        const unsigned short* wq = wb + WOFF_QKV + l * 110592;
        // q (scale folded into weights): bf16 [N][192]
        mfma_gemm<0, 0, 96, 192><<<dim3(313, 2), blk, 0, stream>>>(hH, hL, N_NODES, 192,
            wq, nullptr, nullptr, nullptr, nullptr, nullptr, qB, nullptr, 192, 1, 0);
        // k -> kv even slots
        mfma_gemm<0, 0, 96, 192><<<dim3(313, 2), blk, 0, stream>>>(hH, hL, N_NODES, 192,
            wq + 192 * 192, nullptr, nullptr, nullptr, nullptr, nullptr, kvB, nullptr, 384, 2, 0);
        // v -> kv odd slots
        mfma_gemm<0, 0, 96, 192><<<dim3(313, 2), blk, 0, stream>>>(hH, hL, N_NODES, 192,
            wq + 384 * 192, nullptr, nullptr, nullptr, nullptr, nullptr, kvB, nullptr, 384, 2, 1);
        attn_kernel<<<10000, blk, 0, stream>>>(qB, kvB, ea, We + l * 768, csr2, rowp, msgH, msgL);
        mfma_gemm<2, 1, 192, 96><<<dim3(313, 1), blk, 0, stream>>>(msgH, msgL, N_NODES, 192,
            wb + WOFF_WO + l * 36864, bo + l * 192, hH, hL, ln1g + l * 192, ln1b + l * 192,
            htH, htL, 192, 1, 0);
        mfma_gemm<1, 1, 96, 192><<<dim3(313, 4), blk, 0, stream>>>(htH, htL, N_NODES, 192,
            wb + WOFF_WF1 + l * 73728, bf1 + l * 384, nullptr, nullptr, nullptr, nullptr,
            ffH, ffL, 384, 1, 0);
        mfma_gemm<2, 1, 192, 96><<<dim3(313, 1), blk, 0, stream>>>(ffH, ffL, N_NODES, 384,
            wb + WOFF_WF2 + l * 73728, bf2 + l * 192, htH, htL, ln2g + l * 192, ln2b + l * 192,
            hH, hL, 192, 1, 0);
    }

    // edge head pre-projections: [Hs|Hd] = h @ [We1[0:192] | We1[192:384]] -> bf16
    mfma_gemm<0, 0, 96, 192><<<dim3(313, 4), blk, 0, stream>>>(hH, hL, N_NODES, 192,
        wb + WOFF_HSD, nullptr, nullptr, nullptr, nullptr, nullptr, hsdB, nullptr, 384, 1, 0);
    edge_head_kernel<<<6250, blk, 0, stream>>>(hsdB, ea, src, dst,
        We1 + 384 * 192, be1, wb + WOFF_WE2, be2, We3, be3, (float*)d_out);
}

// Round 5
// 930.839 us; speedup vs baseline: 1.2974x; 1.0814x over previous
//
#include <hip/hip_runtime.h>
#include <hip/hip_bf16.h>
#include <math.h>

#define N_NODES 40000
#define N_EDGES 400000
#define GCLIP 511

using short8  = __attribute__((ext_vector_type(8))) short;
using ushort8 = __attribute__((ext_vector_type(8))) unsigned short;
using floatx4 = __attribute__((ext_vector_type(4))) float;

__device__ __forceinline__ void split_bf16(float v, unsigned short& hi, unsigned short& lo) {
    __hip_bfloat16 h = __float2bfloat16(v);
    float r = v - __bfloat162float(h);
    __hip_bfloat16 l = __float2bfloat16(r);
    hi = *(unsigned short*)&h;
    lo = *(unsigned short*)&l;
}
__device__ __forceinline__ unsigned short f2bf(float f) {
    __hip_bfloat16 h = __float2bfloat16(f);
    return *(unsigned short*)&h;
}
__device__ __forceinline__ float bf2f(unsigned short u) {
    __hip_bfloat16 h = *(__hip_bfloat16*)&u;
    return __bfloat162float(h);
}
__device__ __forceinline__ floatx4 mfma16(short8 a, short8 b, floatx4 c) {
    return __builtin_amdgcn_mfma_f32_16x16x32_bf16(a, b, c, 0, 0, 0);
}

// ---------------- CSR build ----------------
__global__ void count_kernel(const int* __restrict__ dst, int* __restrict__ cnt, int E) {
    int e = blockIdx.x * 256 + threadIdx.x;
    if (e < E) atomicAdd(&cnt[dst[e]], 1);
}

__global__ void scan1_kernel(const int* __restrict__ cnt, int* __restrict__ rowp,
                             int* __restrict__ bsum, int n) {
    __shared__ int wsum[16];
    __shared__ int woff[16];
    int tid = threadIdx.x, wave = tid >> 6, lane = tid & 63;
    int i = blockIdx.x * 1024 + tid;
    int v = (i < n) ? cnt[i] : 0;
    int x = v;
    for (int off = 1; off < 64; off <<= 1) {
        int t = __shfl_up(x, off);
        if (lane >= off) x += t;
    }
    if (lane == 63) wsum[wave] = x;
    __syncthreads();
    if (wave == 0 && lane < 16) {
        int s = wsum[lane];
        for (int off = 1; off < 16; off <<= 1) {
            int t = __shfl_up(s, off);
            if (lane >= off) s += t;
        }
        woff[lane] = s;
    }
    __syncthreads();
    int incl = x + ((wave == 0) ? 0 : woff[wave - 1]);
    if (i < n) rowp[i] = incl - v;
    if (tid == 1023) bsum[blockIdx.x] = incl;
}

__global__ void scan2_kernel(const int* __restrict__ bsum, int* __restrict__ boffs,
                             int* __restrict__ rowp, int nb, int n) {
    int lane = threadIdx.x;
    int v = (lane < nb) ? bsum[lane] : 0;
    int x = v;
    for (int off = 1; off < 64; off <<= 1) {
        int t = __shfl_up(x, off);
        if (lane >= off) x += t;
    }
    if (lane < nb) boffs[lane] = x - v;
    if (lane == nb - 1) rowp[n] = x;
}

__global__ void scan3_kernel(int* __restrict__ rowp, int* __restrict__ curs,
                             const int* __restrict__ boffs, int n) {
    int i = blockIdx.x * 1024 + threadIdx.x;
    if (i < n) {
        int v = rowp[i] + boffs[blockIdx.x];
        rowp[i] = v;
        curs[i] = v;
    }
}

__global__ void scatter_kernel(const int* __restrict__ src, const int* __restrict__ dst,
                               int* __restrict__ cursor, int2* __restrict__ csr2, int E) {
    int e = blockIdx.x * 256 + threadIdx.x;
    if (e < E) {
        int pos = atomicAdd(&cursor[dst[e]], 1);
        csr2[pos] = make_int2(src[e], e);
    }
}

// ---------------- feature build -> bf16 hi/lo planes [N][32] (cols 16..31 zero) -------
__global__ void feat_kernel(const float* __restrict__ x, const int* __restrict__ batch,
                            const int* __restrict__ gptr, const int* __restrict__ tgid,
                            const float* __restrict__ gp, const float* __restrict__ sp,
                            const float* __restrict__ ep,
                            unsigned short* __restrict__ fhi, unsigned short* __restrict__ flo,
                            int n) {
    int idx = blockIdx.x * 256 + threadIdx.x;
    if (idx >= n * 32) return;
    int node = idx >> 5, c = idx & 31;
    float v = 0.f;
    if (c < 4) {
        v = x[node * 4 + c];
    } else if (c < 7) {
        int gid = gptr[batch[node]] + tgid[node];
        gid = min(max(gid, 0), GCLIP);
        v = gp[gid * 3 + (c - 4)];
    } else if (c < 10) {
        v = sp[node * 3 + (c - 7)];
    } else if (c < 16) {
        int gid = gptr[batch[node]] + tgid[node];
        gid = min(max(gid, 0), GCLIP);
        v = ep[gid * 6 + (c - 10)];
    }
    unsigned short hi, lo;
    split_bf16(v, hi, lo);
    fhi[idx] = hi;
    flo[idx] = lo;
}

// ---------------- weight prep: transpose to [Nrows][Ka] bf16 (hi only) ----------------
#define WOFF_WIN 0
#define WOFF_QKV 6144
#define WOFF_WO  337920
#define WOFF_WF1 448512
#define WOFF_WF2 669696
#define WOFF_HSD 890880
#define WOFF_WE2 964608
#define WTOT     983040

__global__ void prep_kernel(const float* __restrict__ W_in, const float* __restrict__ Wq,
                            const float* __restrict__ Wk, const float* __restrict__ Wv,
                            const float* __restrict__ Wo, const float* __restrict__ Wf1,
                            const float* __restrict__ Wf2, const float* __restrict__ We1,
                            const float* __restrict__ We2, unsigned short* __restrict__ wb) {
    int idx = blockIdx.x * 256 + threadIdx.x;
    if (idx >= WTOT) return;
    float val;
    if (idx < WOFF_QKV) {                       // W_in^T [192][32], K=16 padded
        int n = idx / 32, k = idx % 32;
        val = (k < 16) ? W_in[k * 192 + n] : 0.f;
    } else if (idx < WOFF_WO) {                 // Wqkv^T [576][192] x3; q rows pre-scaled
        int r = idx - WOFF_QKV; int l = r / 110592; r %= 110592;
        int n = r / 192, k = r % 192;
        const float* s = (n < 192) ? Wq : (n < 384 ? Wk : Wv);
        val = s[l * 36864 + k * 192 + (n % 192)];
        if (n < 192) val *= 0.14433756729740643f;   // 1/sqrt(48) folded into Wq
    } else if (idx < WOFF_WF1) {                // Wo^T [192][192] x3
        int r = idx - WOFF_WO; int l = r / 36864; r %= 36864;
        int n = r / 192, k = r % 192;
        val = Wo[l * 36864 + k * 192 + n];
    } else if (idx < WOFF_WF2) {                // Wf1^T [384][192] x3
        int r = idx - WOFF_WF1; int l = r / 73728; r %= 73728;
        int n = r / 192, k = r % 192;
        val = Wf1[l * 73728 + k * 384 + n];
    } else if (idx < WOFF_HSD) {                // Wf2^T [192][384] x3
        int r = idx - WOFF_WF2; int l = r / 73728; r %= 73728;
        int n = r / 384, k = r % 384;
        val = Wf2[l * 73728 + k * 192 + n];
    } else if (idx < WOFF_WE2) {                // [Hs|Hd]^T [384][192]
        int r = idx - WOFF_HSD;
        int n = r / 192, k = r % 192;
        val = (n < 192) ? We1[k * 192 + n] : We1[(192 + k) * 192 + (n - 192)];
    } else {                                    // We2^T [96][192]
        int r = idx - WOFF_WE2;
        int n = r / 192, k = r % 192;
        val = We2[k * 96 + n];
    }
    wb[idx] = f2bf(val);
}

// ---------------- MFMA GEMM: A global bf16 planes (prefetched), B in LDS --------------
// BM=128 (4 waves x 32 rows). TERMS: 1 = A-hi only, 2 = hi+lo.
// EPI: 0 none, 1 relu, 2 bias+resid+LN (BN=192, grid.y=1).
// OUTMODE: 0 linear (oldc/cmul/cadd), 1 qkv piecewise (Chi=qB, Clo=kv interleaved).
template <int EPI, int DUAL, int BN, int KCH, int TERMS, int OUTMODE>
__global__ __launch_bounds__(256, 2)
void mfma_gemm(const unsigned short* __restrict__ Ahi, const unsigned short* __restrict__ Alo,
               int M, int Ka,
               const unsigned short* __restrict__ B, const float* __restrict__ bias,
               const unsigned short* __restrict__ Rhi, const unsigned short* __restrict__ Rlo,
               const float* __restrict__ lng, const float* __restrict__ lnb,
               unsigned short* __restrict__ Chi, unsigned short* __restrict__ Clo,
               int oldc, int cmul, int cadd) {
    constexpr int NT = BN / 16;
    __shared__ __align__(16) unsigned short sB[BN][KCH + 8];
    const int tid = threadIdx.x;
    const int wave = tid >> 6, lane = tid & 63;
    const int quad = lane >> 4, l16 = lane & 15;
    const int rbase = blockIdx.x * 128;
    const int cbase = blockIdx.y * BN;

    floatx4 acc[2][NT];
#pragma unroll
    for (int mt = 0; mt < 2; ++mt)
#pragma unroll
        for (int nt = 0; nt < NT; ++nt) acc[mt][nt] = (floatx4)0.0f;

    const int r0 = min(rbase + wave * 32 + l16, M - 1);
    const int r1 = min(rbase + wave * 32 + 16 + l16, M - 1);
    const unsigned short* pa0h = Ahi + (size_t)r0 * Ka + quad * 8;
    const unsigned short* pa1h = Ahi + (size_t)r1 * Ka + quad * 8;
    const unsigned short* pa0l = Alo + (size_t)r0 * Ka + quad * 8;
    const unsigned short* pa1l = Alo + (size_t)r1 * Ka + quad * 8;

    for (int kb = 0; kb < Ka; kb += KCH) {
        if (kb) __syncthreads();
        for (int i = tid * 8; i < BN * KCH; i += 2048) {
            int n = i / KCH, kk = i % KCH;
            *(uint4*)&sB[n][kk] = *(const uint4*)(B + (size_t)(cbase + n) * Ka + kb + kk);
        }
        __syncthreads();
        // rolling A-fragment prefetch
        short8 ch0 = *(const short8*)(pa0h + kb);
        short8 ch1 = *(const short8*)(pa1h + kb);
        short8 cl0, cl1;
        if (TERMS == 2) {
            cl0 = *(const short8*)(pa0l + kb);
            cl1 = *(const short8*)(pa1l + kb);
        }
#pragma unroll
        for (int kc = 0; kc < KCH; kc += 32) {
            short8 nh0 = ch0, nh1 = ch1, nl0 = ch0, nl1 = ch1;
            if (kc + 32 < KCH) {
                nh0 = *(const short8*)(pa0h + kb + kc + 32);
                nh1 = *(const short8*)(pa1h + kb + kc + 32);
                if (TERMS == 2) {
                    nl0 = *(const short8*)(pa0l + kb + kc + 32);
                    nl1 = *(const short8*)(pa1l + kb + kc + 32);
                }
            }
#pragma unroll
            for (int nt = 0; nt < NT; ++nt) {
                short8 b = *(const short8*)&sB[nt * 16 + l16][kc + quad * 8];
                acc[0][nt] = mfma16(ch0, b, acc[0][nt]);
                if (TERMS == 2) acc[0][nt] = mfma16(cl0, b, acc[0][nt]);
                acc[1][nt] = mfma16(ch1, b, acc[1][nt]);
                if (TERMS == 2) acc[1][nt] = mfma16(cl1, b, acc[1][nt]);
            }
            ch0 = nh0; ch1 = nh1;
            if (TERMS == 2) { cl0 = nl0; cl1 = nl1; }
        }
    }

    float bb[NT], gg[NT], be[NT];
#pragma unroll
    for (int nt = 0; nt < NT; ++nt) {
        int colg = cbase + nt * 16 + l16;
        bb[nt] = bias ? bias[colg] : 0.f;
        if (EPI == 2) { gg[nt] = lng[colg]; be[nt] = lnb[colg]; }
    }
#pragma unroll
    for (int mt = 0; mt < 2; ++mt) {
#pragma unroll
        for (int reg = 0; reg < 4; ++reg) {
            int row = rbase + wave * 32 + mt * 16 + quad * 4 + reg;
            if (EPI == 2) {
                int rr = min(row, M - 1);
                float v[NT], s = 0.f, q = 0.f;
#pragma unroll
                for (int nt = 0; nt < NT; ++nt) {
                    size_t off = (size_t)rr * 192 + nt * 16 + l16;
                    float resid = bf2f(Rhi[off]) + bf2f(Rlo[off]);
                    v[nt] = acc[mt][nt][reg] + bb[nt] + resid;
                    s += v[nt]; q += v[nt] * v[nt];
                }
#pragma unroll
                for (int off = 1; off < 16; off <<= 1) {
                    s += __shfl_xor(s, off);
                    q += __shfl_xor(q, off);
                }
                float mean = s * (1.f / 192.f);
                float var = q * (1.f / 192.f) - mean * mean;
                float rs = rsqrtf(var + 1e-5f);
                if (row < M) {
#pragma unroll
                    for (int nt = 0; nt < NT; ++nt) {
                        float r = (v[nt] - mean) * rs * gg[nt] + be[nt];
                        unsigned short hi, lo;
                        split_bf16(r, hi, lo);
                        size_t off = (size_t)row * 192 + nt * 16 + l16;
                        Chi[off] = hi; Clo[off] = lo;
                    }
                }
            } else if (row < M) {
#pragma unroll
                for (int nt = 0; nt < NT; ++nt) {
                    float v = acc[mt][nt][reg] + bb[nt];
                    if (EPI == 1) v = fmaxf(v, 0.f);
                    if (OUTMODE == 1) {
                        int c = cbase + nt * 16 + l16;
                        if (c < 192) {
                            Chi[(size_t)row * 192 + c] = f2bf(v);
                        } else {
                            int cc = c - 192;
                            int idx = (cc < 192) ? (cc * 2) : ((cc - 192) * 2 + 1);
                            Clo[(size_t)row * 384 + idx] = f2bf(v);
                        }
                    } else {
                        size_t off = (size_t)row * oldc + (size_t)(cbase + nt * 16 + l16) * cmul + cadd;
                        if (DUAL) {
                            unsigned short hi, lo;
                            split_bf16(v, hi, lo);
                            Chi[off] = hi; Clo[off] = lo;
                        } else {
                            Chi[off] = f2bf(v);
                        }
                    }
                }
            }
        }
    }
}

// ---------------- edge attention: q bf16 [N][192] (pre-scaled), kv interleaved --------
// logit = q.k[s] + qe.w_e ; msg = (sum p*v + (sum p*w_e)@We)/den  (exact factoring)
// 4-edge unroll: independent dot/exp chains merged associatively.
__global__ __launch_bounds__(256)
void attn_kernel(const unsigned short* __restrict__ qB, const unsigned short* __restrict__ kvB,
                 const float* __restrict__ ea, const float* __restrict__ We_l,
                 const int2* __restrict__ csr2, const int* __restrict__ row_ptr,
                 unsigned short* __restrict__ msg_hi, unsigned short* __restrict__ msg_lo) {
    __shared__ float sWe[768];
    const int tid = threadIdx.x;
    for (int i = tid; i < 768; i += 256) sWe[i] = We_l[i];
    __syncthreads();

    const int lane = tid & 63;
    const int node = blockIdx.x * 4 + (tid >> 6);
    const int d0 = (lane >> 4) * 48 + (lane & 15) * 3;

    float W[4][3];
#pragma unroll
    for (int w = 0; w < 4; ++w) {
        W[w][0] = sWe[w * 192 + d0];
        W[w][1] = sWe[w * 192 + d0 + 1];
        W[w][2] = sWe[w * 192 + d0 + 2];
    }
    size_t qoff = (size_t)node * 192 + d0;
    float q0 = bf2f(qB[qoff]), q1 = bf2f(qB[qoff + 1]), q2 = bf2f(qB[qoff + 2]);
    float qe0 = q0 * W[0][0] + q1 * W[0][1] + q2 * W[0][2];
    float qe1 = q0 * W[1][0] + q1 * W[1][1] + q2 * W[1][2];
    float qe2 = q0 * W[2][0] + q1 * W[2][1] + q2 * W[2][2];
    float qe3 = q0 * W[3][0] + q1 * W[3][1] + q2 * W[3][2];
#pragma unroll
    for (int off = 1; off < 16; off <<= 1) {
        qe0 += __shfl_xor(qe0, off);
        qe1 += __shfl_xor(qe1, off);
        qe2 += __shfl_xor(qe2, off);
        qe3 += __shfl_xor(qe3, off);
    }

    const unsigned int* kv = (const unsigned int*)kvB;
    const float4* ea4 = (const float4*)ea;

    float m = -INFINITY, den = 0.f;
    float v0 = 0.f, v1 = 0.f, v2 = 0.f;
    float wa0 = 0.f, wa1 = 0.f, wa2 = 0.f, wa3 = 0.f;
    const int beg = row_ptr[node], end = row_ptr[node + 1];
    int p = beg;
    for (; p + 3 < end; p += 4) {
        int2 seA = csr2[p], seB = csr2[p + 1], seC = csr2[p + 2], seD = csr2[p + 3];
        size_t bA = (size_t)seA.x * 192 + d0;
        size_t bB = (size_t)seB.x * 192 + d0;
        size_t bC = (size_t)seC.x * 192 + d0;
        size_t bD = (size_t)seD.x * 192 + d0;
        unsigned int uA0 = kv[bA], uA1 = kv[bA + 1], uA2 = kv[bA + 2];
        unsigned int uB0 = kv[bB], uB1 = kv[bB + 1], uB2 = kv[bB + 2];
        unsigned int uC0 = kv[bC], uC1 = kv[bC + 1], uC2 = kv[bC + 2];
        unsigned int uD0 = kv[bD], uD1 = kv[bD + 1], uD2 = kv[bD + 2];
        float4 wA = ea4[seA.y], wB = ea4[seB.y], wC = ea4[seC.y], wD = ea4[seD.y];
        float dA = q0 * bf2f((unsigned short)uA0) + q1 * bf2f((unsigned short)uA1) + q2 * bf2f((unsigned short)uA2);
        float dB = q0 * bf2f((unsigned short)uB0) + q1 * bf2f((unsigned short)uB1) + q2 * bf2f((unsigned short)uB2);
        float dC = q0 * bf2f((unsigned short)uC0) + q1 * bf2f((unsigned short)uC1) + q2 * bf2f((unsigned short)uC2);
        float dD = q0 * bf2f((unsigned short)uD0) + q1 * bf2f((unsigned short)uD1) + q2 * bf2f((unsigned short)uD2);
#pragma unroll
        for (int off = 1; off < 16; off <<= 1) {
            dA += __shfl_xor(dA, off);
            dB += __shfl_xor(dB, off);
            dC += __shfl_xor(dC, off);
            dD += __shfl_xor(dD, off);
        }
        float lA = dA + wA.x * qe0 + wA.y * qe1 + wA.z * qe2 + wA.w * qe3;
        float lB = dB + wB.x * qe0 + wB.y * qe1 + wB.z * qe2 + wB.w * qe3;
        float lC = dC + wC.x * qe0 + wC.y * qe1 + wC.z * qe2 + wC.w * qe3;
        float lD = dD + wD.x * qe0 + wD.y * qe1 + wD.z * qe2 + wD.w * qe3;
        float mn = fmaxf(m, fmaxf(fmaxf(lA, lB), fmaxf(lC, lD)));
        float corr = __expf(m - mn);
        float pA = __expf(lA - mn), pB = __expf(lB - mn);
        float pC = __expf(lC - mn), pD = __expf(lD - mn);
        den = den * corr + pA + pB + pC + pD;
        v0 = v0 * corr + pA * bf2f((unsigned short)(uA0 >> 16)) + pB * bf2f((unsigned short)(uB0 >> 16))
                       + pC * bf2f((unsigned short)(uC0 >> 16)) + pD * bf2f((unsigned short)(uD0 >> 16));
        v1 = v1 * corr + pA * bf2f((unsigned short)(uA1 >> 16)) + pB * bf2f((unsigned short)(uB1 >> 16))
                       + pC * bf2f((unsigned short)(uC1 >> 16)) + pD * bf2f((unsigned short)(uD1 >> 16));
        v2 = v2 * corr + pA * bf2f((unsigned short)(uA2 >> 16)) + pB * bf2f((unsigned short)(uB2 >> 16))
                       + pC * bf2f((unsigned short)(uC2 >> 16)) + pD * bf2f((unsigned short)(uD2 >> 16));
        wa0 = wa0 * corr + pA * wA.x + pB * wB.x + pC * wC.x + pD * wD.x;
        wa1 = wa1 * corr + pA * wA.y + pB * wB.y + pC * wC.y + pD * wD.y;
        wa2 = wa2 * corr + pA * wA.z + pB * wB.z + pC * wC.z + pD * wD.z;
        wa3 = wa3 * corr + pA * wA.w + pB * wB.w + pC * wC.w + pD * wD.w;
        m = mn;
    }
    for (; p < end; ++p) {
        int2 se = csr2[p];
        size_t b = (size_t)se.x * 192 + d0;
        unsigned int u0 = kv[b], u1 = kv[b + 1], u2 = kv[b + 2];
        float4 w = ea4[se.y];
        float d = q0 * bf2f((unsigned short)u0) + q1 * bf2f((unsigned short)u1)
                + q2 * bf2f((unsigned short)u2);
#pragma unroll
        for (int off = 1; off < 16; off <<= 1) d += __shfl_xor(d, off);
        float l = d + w.x * qe0 + w.y * qe1 + w.z * qe2 + w.w * qe3;
        float mn = fmaxf(m, l);
        float corr = __expf(m - mn);
        float pe = __expf(l - mn);
        den = den * corr + pe;
        v0 = v0 * corr + pe * bf2f((unsigned short)(u0 >> 16));
        v1 = v1 * corr + pe * bf2f((unsigned short)(u1 >> 16));
        v2 = v2 * corr + pe * bf2f((unsigned short)(u2 >> 16));
        wa0 = wa0 * corr + pe * w.x;
        wa1 = wa1 * corr + pe * w.y;
        wa2 = wa2 * corr + pe * w.z;
        wa3 = wa3 * corr + pe * w.w;
        m = mn;
    }
    float inv = 1.f / (den + 1e-16f);
    float m0 = (v0 + wa0 * W[0][0] + wa1 * W[1][0] + wa2 * W[2][0] + wa3 * W[3][0]) * inv;
    float m1 = (v1 + wa0 * W[0][1] + wa1 * W[1][1] + wa2 * W[2][1] + wa3 * W[3][1]) * inv;
    float m2 = (v2 + wa0 * W[0][2] + wa1 * W[1][2] + wa2 * W[2][2] + wa3 * W[3][2]) * inv;
    size_t ob = (size_t)node * 192 + d0;
    unsigned short hi, lo;
    split_bf16(m0, hi, lo); msg_hi[ob] = hi;     msg_lo[ob] = lo;
    split_bf16(m1, hi, lo); msg_hi[ob + 1] = hi; msg_lo[ob + 1] = lo;
    split_bf16(m2, hi, lo); msg_hi[ob + 2] = hi; msg_lo[ob + 2] = lo;
}

// ---------------- edge head: register A-fragments, no sZ, W2 LDS-resident -------------
// Wave handles 16 edges: lane (quad,l16) owns edge l16, columns quad*8+j -> exact
// MFMA A-fragment layout. K-loop has zero barriers and zero LDS staging.
__global__ __launch_bounds__(256, 2)
void edge_head_kernel(const unsigned short* __restrict__ hsd, const float* __restrict__ ea,
                      const int* __restrict__ src, const int* __restrict__ dst,
                      const float* __restrict__ W1e, const float* __restrict__ b1,
                      const unsigned short* __restrict__ W2hi,
                      const float* __restrict__ b2, const float* __restrict__ W3,
                      const float* __restrict__ b3, float* __restrict__ out) {
    __shared__ __align__(16) unsigned short sW[96][200];
    __shared__ __align__(16) float sWe1[768];
    __shared__ __align__(16) float sB1[192];
    const int tid = threadIdx.x;
    const int wave = tid >> 6, lane = tid & 63;
    const int quad = lane >> 4, l16 = lane & 15;
    const int ebase = blockIdx.x * 64;

    for (int i = tid; i < 768; i += 256) sWe1[i] = W1e[i];
    if (tid < 192) sB1[tid] = b1[tid];
    for (int i = tid * 8; i < 96 * 192; i += 2048) {
        int n = i / 192, kk = i % 192;
        *(uint4*)&sW[n][kk] = *(const uint4*)(W2hi + (size_t)n * 192 + kk);
    }

    const int e = ebase + wave * 16 + l16;        // this lane's edge
    const int s = src[e], d = dst[e];
    const float4 eav = *(const float4*)(ea + (size_t)e * 4);
    const unsigned short* hs_p = hsd + (size_t)s * 384 + quad * 8;
    const unsigned short* hd_p = hsd + (size_t)d * 384 + 192 + quad * 8;

    floatx4 acc[6];
#pragma unroll
    for (int nt = 0; nt < 6; ++nt) acc[nt] = (floatx4)0.0f;
    __syncthreads();

    ushort8 hs_c = *(const ushort8*)hs_p;
    ushort8 hd_c = *(const ushort8*)hd_p;
#pragma unroll
    for (int kc = 0; kc < 192; kc += 32) {
        ushort8 hs_n = hs_c, hd_n = hd_c;
        if (kc + 32 < 192) {
            hs_n = *(const ushort8*)(hs_p + kc + 32);
            hd_n = *(const ushort8*)(hd_p + kc + 32);
        }
        const int c0 = kc + quad * 8;
        float wb1[8], w0v[8], w1v[8], w2v[8], w3v[8];
        *(float4*)&wb1[0] = *(const float4*)&sB1[c0];
        *(float4*)&wb1[4] = *(const float4*)&sB1[c0 + 4];
        *(float4*)&w0v[0] = *(const float4*)&sWe1[c0];
        *(float4*)&w0v[4] = *(const float4*)&sWe1[c0 + 4];
        *(float4*)&w1v[0] = *(const float4*)&sWe1[192 + c0];
        *(float4*)&w1v[4] = *(const float4*)&sWe1[192 + c0 + 4];
        *(float4*)&w2v[0] = *(const float4*)&sWe1[384 + c0];
        *(float4*)&w2v[4] = *(const float4*)&sWe1[384 + c0 + 4];
        *(float4*)&w3v[0] = *(const float4*)&sWe1[576 + c0];
        *(float4*)&w3v[4] = *(const float4*)&sWe1[576 + c0 + 4];
        ushort8 ah, al;
#pragma unroll
        for (int j = 0; j < 8; ++j) {
            float ce = wb1[j] + eav.x * w0v[j] + eav.y * w1v[j]
                     + eav.z * w2v[j] + eav.w * w3v[j];
            float v = fmaxf(bf2f(hs_c[j]) + bf2f(hd_c[j]) + ce, 0.f);
            unsigned short hi, lo;
            split_bf16(v, hi, lo);
            ah[j] = hi; al[j] = lo;
        }
        short8 ahs = *(short8*)&ah, als = *(short8*)&al;
#pragma unroll
        for (int nt = 0; nt < 6; ++nt) {
            short8 bh = *(const short8*)&sW[nt * 16 + l16][kc + quad * 8];
            acc[nt] = mfma16(ahs, bh, acc[nt]);
            acc[nt] = mfma16(als, bh, acc[nt]);
        }
        hs_c = hs_n; hd_c = hd_n;
    }

    float w3[6], bb2[6];
#pragma unroll
    for (int nt = 0; nt < 6; ++nt) {
        int col = nt * 16 + l16;
        w3[nt] = W3[col];
        bb2[nt] = b2[col];
    }
    float b3v = b3[0];
#pragma unroll
    for (int reg = 0; reg < 4; ++reg) {
        float sacc = 0.f;
#pragma unroll
        for (int nt = 0; nt < 6; ++nt) {
            float z = fmaxf(acc[nt][reg] + bb2[nt], 0.f);
            sacc = fmaf(z, w3[nt], sacc);
        }
#pragma unroll
        for (int off = 1; off < 16; off <<= 1) sacc += __shfl_xor(sacc, off);
        if (l16 == 0) out[ebase + wave * 16 + quad * 4 + reg] = sacc + b3v;
    }
}

extern "C" void kernel_launch(void* const* d_in, const int* in_sizes, int n_in,
                              void* d_out, int out_size, void* d_ws, size_t ws_size,
                              hipStream_t stream) {
    const float* x     = (const float*)d_in[0];
    const int*   eidx  = (const int*)d_in[1];
    const float* ea    = (const float*)d_in[2];
    const int*   batch = (const int*)d_in[3];
    const int*   gptr  = (const int*)d_in[4];
    const int*   tgid  = (const int*)d_in[5];
    const float* gp    = (const float*)d_in[6];
    const float* sp    = (const float*)d_in[7];
    const float* epp   = (const float*)d_in[8];
    const float* W_in  = (const float*)d_in[9];
    const float* b_in  = (const float*)d_in[10];
    const float* Wq    = (const float*)d_in[11];
    const float* Wk    = (const float*)d_in[12];
    const float* Wv    = (const float*)d_in[13];
    const float* We    = (const float*)d_in[14];
    const float* Wo    = (const float*)d_in[15];
    const float* bo    = (const float*)d_in[16];
    const float* ln1g  = (const float*)d_in[17];
    const float* ln1b  = (const float*)d_in[18];
    const float* Wf1   = (const float*)d_in[19];
    const float* bf1   = (const float*)d_in[20];
    const float* Wf2   = (const float*)d_in[21];
    const float* bf2   = (const float*)d_in[22];
    const float* ln2g  = (const float*)d_in[23];
    const float* ln2b  = (const float*)d_in[24];
    const float* We1   = (const float*)d_in[25];
    const float* be1   = (const float*)d_in[26];
    const float* We2   = (const float*)d_in[27];
    const float* be2   = (const float*)d_in[28];
    const float* We3   = (const float*)d_in[29];
    const float* be3   = (const float*)d_in[30];
    const int* src = eidx;
    const int* dst = eidx + N_EDGES;

    unsigned short* ub = (unsigned short*)d_ws;
    unsigned short* featH = ub;                  // 40000*32
    unsigned short* featL = ub + 1280000;
    unsigned short* hH    = ub + 2560000;        // 40000*192 each
    unsigned short* hL    = ub + 10240000;
    unsigned short* htH   = ub + 17920000;
    unsigned short* htL   = ub + 25600000;
    unsigned short* msgH  = ub + 33280000;
    unsigned short* msgL  = ub + 40960000;
    unsigned short* rbuf  = ub + 48640000;       // 40000*768 region
    unsigned short* qB    = rbuf;                // 40000*192
    unsigned short* kvB   = rbuf + 7680000;      // 40000*384 interleaved k/v
    unsigned short* ffH   = rbuf;                // 40000*384 (after attn)
    unsigned short* ffL   = rbuf + 15360000;
    unsigned short* hsdB  = rbuf;                // 40000*384
    unsigned short* wb    = ub + 79360000;       // WTOT
    int* ib   = (int*)(ub + 80343040);
    int* cnt  = ib;
    int* rowp = ib + 40000;
    int* curs = ib + 80004;
    int2* csr2 = (int2*)(ib + 120004);
    int* bsum  = ib + 920004;
    int* boffs = ib + 920044;

    hipMemsetAsync(cnt, 0, N_NODES * sizeof(int), stream);
    count_kernel<<<1563, 256, 0, stream>>>(dst, cnt, N_EDGES);
    scan1_kernel<<<40, 1024, 0, stream>>>(cnt, rowp, bsum, N_NODES);
    scan2_kernel<<<1, 64, 0, stream>>>(bsum, boffs, rowp, 40, N_NODES);
    scan3_kernel<<<40, 1024, 0, stream>>>(rowp, curs, boffs, N_NODES);
    scatter_kernel<<<1563, 256, 0, stream>>>(src, dst, curs, csr2, N_EDGES);
    feat_kernel<<<5000, 256, 0, stream>>>(x, batch, gptr, tgid, gp, sp, epp, featH, featL, N_NODES);
    prep_kernel<<<3840, 256, 0, stream>>>(W_in, Wq, Wk, Wv, Wo, Wf1, Wf2, We1, We2, wb);

    dim3 blk(256);
    // input projection: feat[40000, K=32 planes] @ W_in -> h planes
    mfma_gemm<0, 1, 96, 32, 2, 0><<<dim3(313, 2), blk, 0, stream>>>(featH, featL, N_NODES, 32,
        wb + WOFF_WIN, b_in, nullptr, nullptr, nullptr, nullptr, hH, hL, 192, 1, 0);

    for (int l = 0; l < 3; ++l) {
        const unsigned short* wq = wb + WOFF_QKV + l * 110592;
        // fused qkv: 576 cols; q -> qB, k/v -> kvB interleaved. Single-term A (hi only).
        mfma_gemm<0, 0, 96, 192, 1, 1><<<dim3(313, 6), blk, 0, stream>>>(hH, hL, N_NODES, 192,
            wq, nullptr, nullptr, nullptr, nullptr, nullptr, qB, kvB, 0, 0, 0);
        attn_kernel<<<10000, blk, 0, stream>>>(qB, kvB, ea, We + l * 768, csr2, rowp, msgH, msgL);
        mfma_gemm<2, 1, 192, 96, 2, 0><<<dim3(313, 1), blk, 0, stream>>>(msgH, msgL, N_NODES, 192,
            wb + WOFF_WO + l * 36864, bo + l * 192, hH, hL, ln1g + l * 192, ln1b + l * 192,
            htH, htL, 192, 1, 0);
        mfma_gemm<1, 1, 96, 192, 2, 0><<<dim3(313, 4), blk, 0, stream>>>(htH, htL, N_NODES, 192,
            wb + WOFF_WF1 + l * 73728, bf1 + l * 384, nullptr, nullptr, nullptr, nullptr,
            ffH, ffL, 384, 1, 0);
        mfma_gemm<2, 1, 192, 96, 2, 0><<<dim3(313, 1), blk, 0, stream>>>(ffH, ffL, N_NODES, 384,
            wb + WOFF_WF2 + l * 73728, bf2 + l * 192, htH, htL, ln2g + l * 192, ln2b + l * 192,
            hH, hL, 192, 1, 0);
    }

    // edge head pre-projections: [Hs|Hd] = h @ [We1[0:192] | We1[192:384]] -> bf16
    mfma_gemm<0, 0, 96, 192, 2, 0><<<dim3(313, 4), blk, 0, stream>>>(hH, hL, N_NODES, 192,
        wb + WOFF_HSD, nullptr, nullptr, nullptr, nullptr, nullptr, hsdB, nullptr, 384, 1, 0);
    edge_head_kernel<<<6250, blk, 0, stream>>>(hsdB, ea, src, dst,
        We1 + 384 * 192, be1, wb + WOFF_WE2, be2, We3, be3, (float*)d_out);
}

// Round 6
// 909.879 us; speedup vs baseline: 1.3273x; 1.0230x over previous
//
#include <hip/hip_runtime.h>
#include <hip/hip_bf16.h>
#include <math.h>

#define N_NODES 40000
#define N_EDGES 400000
#define GCLIP 511

using short8  = __attribute__((ext_vector_type(8))) short;
using ushort8 = __attribute__((ext_vector_type(8))) unsigned short;
using floatx4 = __attribute__((ext_vector_type(4))) float;

__device__ __forceinline__ void split_bf16(float v, unsigned short& hi, unsigned short& lo) {
    __hip_bfloat16 h = __float2bfloat16(v);
    float r = v - __bfloat162float(h);
    __hip_bfloat16 l = __float2bfloat16(r);
    hi = *(unsigned short*)&h;
    lo = *(unsigned short*)&l;
}
__device__ __forceinline__ unsigned short f2bf(float f) {
    __hip_bfloat16 h = __float2bfloat16(f);
    return *(unsigned short*)&h;
}
__device__ __forceinline__ float bf2f(unsigned short u) {
    __hip_bfloat16 h = *(__hip_bfloat16*)&u;
    return __bfloat162float(h);
}
__device__ __forceinline__ floatx4 mfma16(short8 a, short8 b, floatx4 c) {
    return __builtin_amdgcn_mfma_f32_16x16x32_bf16(a, b, c, 0, 0, 0);
}

// ---------------- CSR build ----------------
__global__ void count_kernel(const int* __restrict__ dst, int* __restrict__ cnt, int E) {
    int e = blockIdx.x * 256 + threadIdx.x;
    if (e < E) atomicAdd(&cnt[dst[e]], 1);
}

__global__ void scan1_kernel(const int* __restrict__ cnt, int* __restrict__ rowp,
                             int* __restrict__ bsum, int n) {
    __shared__ int wsum[16];
    __shared__ int woff[16];
    int tid = threadIdx.x, wave = tid >> 6, lane = tid & 63;
    int i = blockIdx.x * 1024 + tid;
    int v = (i < n) ? cnt[i] : 0;
    int x = v;
    for (int off = 1; off < 64; off <<= 1) {
        int t = __shfl_up(x, off);
        if (lane >= off) x += t;
    }
    if (lane == 63) wsum[wave] = x;
    __syncthreads();
    if (wave == 0 && lane < 16) {
        int s = wsum[lane];
        for (int off = 1; off < 16; off <<= 1) {
            int t = __shfl_up(s, off);
            if (lane >= off) s += t;
        }
        woff[lane] = s;
    }
    __syncthreads();
    int incl = x + ((wave == 0) ? 0 : woff[wave - 1]);
    if (i < n) rowp[i] = incl - v;
    if (tid == 1023) bsum[blockIdx.x] = incl;
}

__global__ void scan2_kernel(const int* __restrict__ bsum, int* __restrict__ boffs,
                             int* __restrict__ rowp, int nb, int n) {
    int lane = threadIdx.x;
    int v = (lane < nb) ? bsum[lane] : 0;
    int x = v;
    for (int off = 1; off < 64; off <<= 1) {
        int t = __shfl_up(x, off);
        if (lane >= off) x += t;
    }
    if (lane < nb) boffs[lane] = x - v;
    if (lane == nb - 1) rowp[n] = x;
}

__global__ void scan3_kernel(int* __restrict__ rowp, int* __restrict__ curs,
                             const int* __restrict__ boffs, int n) {
    int i = blockIdx.x * 1024 + threadIdx.x;
    if (i < n) {
        int v = rowp[i] + boffs[blockIdx.x];
        rowp[i] = v;
        curs[i] = v;
    }
}

__global__ void scatter_kernel(const int* __restrict__ src, const int* __restrict__ dst,
                               int* __restrict__ cursor, int2* __restrict__ csr2, int E) {
    int e = blockIdx.x * 256 + threadIdx.x;
    if (e < E) {
        int pos = atomicAdd(&cursor[dst[e]], 1);
        csr2[pos] = make_int2(src[e], e);
    }
}

// ---------------- feature build -> bf16 hi/lo planes [N][32] (cols 16..31 zero) -------
__global__ void feat_kernel(const float* __restrict__ x, const int* __restrict__ batch,
                            const int* __restrict__ gptr, const int* __restrict__ tgid,
                            const float* __restrict__ gp, const float* __restrict__ sp,
                            const float* __restrict__ ep,
                            unsigned short* __restrict__ fhi, unsigned short* __restrict__ flo,
                            int n) {
    int idx = blockIdx.x * 256 + threadIdx.x;
    if (idx >= n * 32) return;
    int node = idx >> 5, c = idx & 31;
    float v = 0.f;
    if (c < 4) {
        v = x[node * 4 + c];
    } else if (c < 7) {
        int gid = gptr[batch[node]] + tgid[node];
        gid = min(max(gid, 0), GCLIP);
        v = gp[gid * 3 + (c - 4)];
    } else if (c < 10) {
        v = sp[node * 3 + (c - 7)];
    } else if (c < 16) {
        int gid = gptr[batch[node]] + tgid[node];
        gid = min(max(gid, 0), GCLIP);
        v = ep[gid * 6 + (c - 10)];
    }
    unsigned short hi, lo;
    split_bf16(v, hi, lo);
    fhi[idx] = hi;
    flo[idx] = lo;
}

// ---------------- weight prep: transpose to [Nrows][Ka] bf16 (hi only) ----------------
#define WOFF_WIN 0
#define WOFF_QKV 6144
#define WOFF_WO  337920
#define WOFF_WF1 448512
#define WOFF_WF2 669696
#define WOFF_HSD 890880
#define WOFF_WE2 964608
#define WTOT     983040

__global__ void prep_kernel(const float* __restrict__ W_in, const float* __restrict__ Wq,
                            const float* __restrict__ Wk, const float* __restrict__ Wv,
                            const float* __restrict__ Wo, const float* __restrict__ Wf1,
                            const float* __restrict__ Wf2, const float* __restrict__ We1,
                            const float* __restrict__ We2, unsigned short* __restrict__ wb) {
    int idx = blockIdx.x * 256 + threadIdx.x;
    if (idx >= WTOT) return;
    float val;
    if (idx < WOFF_QKV) {                       // W_in^T [192][32], K=16 padded
        int n = idx / 32, k = idx % 32;
        val = (k < 16) ? W_in[k * 192 + n] : 0.f;
    } else if (idx < WOFF_WO) {                 // Wqkv^T [576][192] x3; q rows pre-scaled
        int r = idx - WOFF_QKV; int l = r / 110592; r %= 110592;
        int n = r / 192, k = r % 192;
        const float* s = (n < 192) ? Wq : (n < 384 ? Wk : Wv);
        val = s[l * 36864 + k * 192 + (n % 192)];
        if (n < 192) val *= 0.14433756729740643f;   // 1/sqrt(48) folded into Wq
    } else if (idx < WOFF_WF1) {                // Wo^T [192][192] x3
        int r = idx - WOFF_WO; int l = r / 36864; r %= 36864;
        int n = r / 192, k = r % 192;
        val = Wo[l * 36864 + k * 192 + n];
    } else if (idx < WOFF_WF2) {                // Wf1^T [384][192] x3
        int r = idx - WOFF_WF1; int l = r / 73728; r %= 73728;
        int n = r / 192, k = r % 192;
        val = Wf1[l * 73728 + k * 384 + n];
    } else if (idx < WOFF_HSD) {                // Wf2^T [192][384] x3
        int r = idx - WOFF_WF2; int l = r / 73728; r %= 73728;
        int n = r / 384, k = r % 384;
        val = Wf2[l * 73728 + k * 192 + n];
    } else if (idx < WOFF_WE2) {                // [Hs|Hd]^T [384][192]
        int r = idx - WOFF_HSD;
        int n = r / 192, k = r % 192;
        val = (n < 192) ? We1[k * 192 + n] : We1[(192 + k) * 192 + (n - 192)];
    } else {                                    // We2^T [96][192]
        int r = idx - WOFF_WE2;
        int n = r / 192, k = r % 192;
        val = We2[k * 96 + n];
    }
    wb[idx] = f2bf(val);
}

// LDS tile layout: row n holds k-block j (8 ushorts) at block slot (j ^ (n&7)).
// Row stride SBLK blocks with SBLK % 8 == 0 -> stride = SBLK*4 dwords = 0 mod 32,
// so fragment reads resolve to 8 distinct 16B addresses x 8-lane broadcast: conflict-free.

// ---------------- chunked MFMA GEMM (input proj / wo / ff2) ---------------------------
// A global bf16 planes (rolling prefetch); B staged per KCH chunk, swizzled.
template <int EPI, int DUAL, int BN, int KCH, int TERMS>
__global__ __launch_bounds__(256, 2)
void mfma_gemm(const unsigned short* __restrict__ Ahi, const unsigned short* __restrict__ Alo,
               int M, int Ka,
               const unsigned short* __restrict__ B, const float* __restrict__ bias,
               const unsigned short* __restrict__ Rhi, const unsigned short* __restrict__ Rlo,
               const float* __restrict__ lng, const float* __restrict__ lnb,
               unsigned short* __restrict__ Chi, unsigned short* __restrict__ Clo, int ldc) {
    constexpr int NT = BN / 16;
    constexpr int JB = KCH / 8;                   // real k-blocks per row
    constexpr int SBLK = ((JB + 7) / 8) * 8;      // padded to multiple of 8
    __shared__ __align__(16) unsigned short sB[BN * SBLK * 8];
    const int tid = threadIdx.x;
    const int wave = tid >> 6, lane = tid & 63;
    const int quad = lane >> 4, l16 = lane & 15;
    const int rbase = blockIdx.x * 128;
    const int cbase = blockIdx.y * BN;

    floatx4 acc[2][NT];
#pragma unroll
    for (int mt = 0; mt < 2; ++mt)
#pragma unroll
        for (int nt = 0; nt < NT; ++nt) acc[mt][nt] = (floatx4)0.0f;

    const int r0 = min(rbase + wave * 32 + l16, M - 1);
    const int r1 = min(rbase + wave * 32 + 16 + l16, M - 1);
    const unsigned short* pa0h = Ahi + (size_t)r0 * Ka + quad * 8;
    const unsigned short* pa1h = Ahi + (size_t)r1 * Ka + quad * 8;
    const unsigned short* pa0l = Alo + (size_t)r0 * Ka + quad * 8;
    const unsigned short* pa1l = Alo + (size_t)r1 * Ka + quad * 8;

    for (int kb = 0; kb < Ka; kb += KCH) {
        if (kb) __syncthreads();
        for (int i = tid; i < BN * JB; i += 256) {
            int n = i % BN, j = i / BN;
            *(uint4*)&sB[(n * SBLK + (j ^ (n & 7))) * 8] =
                *(const uint4*)(B + (size_t)(cbase + n) * Ka + kb + j * 8);
        }
        __syncthreads();
        short8 ch0 = *(const short8*)(pa0h + kb);
        short8 ch1 = *(const short8*)(pa1h + kb);
        short8 cl0, cl1;
        if (TERMS == 2) {
            cl0 = *(const short8*)(pa0l + kb);
            cl1 = *(const short8*)(pa1l + kb);
        }
#pragma unroll
        for (int kc = 0; kc < KCH; kc += 32) {
            short8 nh0 = ch0, nh1 = ch1, nl0 = ch0, nl1 = ch1;
            if (kc + 32 < KCH) {
                nh0 = *(const short8*)(pa0h + kb + kc + 32);
                nh1 = *(const short8*)(pa1h + kb + kc + 32);
                if (TERMS == 2) {
                    nl0 = *(const short8*)(pa0l + kb + kc + 32);
                    nl1 = *(const short8*)(pa1l + kb + kc + 32);
                }
            }
            const int jbase = kc / 8;
#pragma unroll
            for (int nt = 0; nt < NT; ++nt) {
                int jj = (jbase + quad) ^ (l16 & 7);
                short8 b = *(const short8*)&sB[((nt * 16 + l16) * SBLK + jj) * 8];
                acc[0][nt] = mfma16(ch0, b, acc[0][nt]);
                if (TERMS == 2) acc[0][nt] = mfma16(cl0, b, acc[0][nt]);
                acc[1][nt] = mfma16(ch1, b, acc[1][nt]);
                if (TERMS == 2) acc[1][nt] = mfma16(cl1, b, acc[1][nt]);
            }
            ch0 = nh0; ch1 = nh1;
            if (TERMS == 2) { cl0 = nl0; cl1 = nl1; }
        }
    }

    float bb[NT], gg[NT], be[NT];
#pragma unroll
    for (int nt = 0; nt < NT; ++nt) {
        int colg = cbase + nt * 16 + l16;
        bb[nt] = bias ? bias[colg] : 0.f;
        if (EPI == 2) { gg[nt] = lng[colg]; be[nt] = lnb[colg]; }
    }
#pragma unroll
    for (int mt = 0; mt < 2; ++mt) {
#pragma unroll
        for (int reg = 0; reg < 4; ++reg) {
            int row = rbase + wave * 32 + mt * 16 + quad * 4 + reg;
            if (EPI == 2) {
                int rr = min(row, M - 1);
                float v[NT], s = 0.f, q = 0.f;
#pragma unroll
                for (int nt = 0; nt < NT; ++nt) {
                    size_t off = (size_t)rr * 192 + nt * 16 + l16;
                    float resid = bf2f(Rhi[off]) + bf2f(Rlo[off]);
                    v[nt] = acc[mt][nt][reg] + bb[nt] + resid;
                    s += v[nt]; q += v[nt] * v[nt];
                }
#pragma unroll
                for (int off = 1; off < 16; off <<= 1) {
                    s += __shfl_xor(s, off);
                    q += __shfl_xor(q, off);
                }
                float mean = s * (1.f / 192.f);
                float var = q * (1.f / 192.f) - mean * mean;
                float rs = rsqrtf(var + 1e-5f);
                if (row < M) {
#pragma unroll
                    for (int nt = 0; nt < NT; ++nt) {
                        float r = (v[nt] - mean) * rs * gg[nt] + be[nt];
                        unsigned short hi, lo;
                        split_bf16(r, hi, lo);
                        size_t off = (size_t)row * 192 + nt * 16 + l16;
                        Chi[off] = hi; Clo[off] = lo;
                    }
                }
            } else if (row < M) {
#pragma unroll
                for (int nt = 0; nt < NT; ++nt) {
                    float v = acc[mt][nt][reg] + bb[nt];
                    if (EPI == 1) v = fmaxf(v, 0.f);
                    size_t off = (size_t)row * ldc + cbase + nt * 16 + l16;
                    if (DUAL) {
                        unsigned short hi, lo;
                        split_bf16(v, hi, lo);
                        Chi[off] = hi; Clo[off] = lo;
                    } else {
                        Chi[off] = f2bf(v);
                    }
                }
            }
        }
    }
}

// ---------------- A-stationary MFMA GEMM (qkv / ff1 / hsd) ----------------------------
// Whole-K A fragments in registers; block loops over NTILES column tiles of BN,
// staging only B per tile. A read exactly once.
// OUTMODE: 0 linear (Chi[,Clo] at ldc), 1 qkv piecewise (Chi=qB[192], Clo=kv ilv[384]).
template <int EPI, int DUAL, int BN, int NTILES, int TERMS, int KF, int OUTMODE>
__global__ __launch_bounds__(256, 2)
void mfma_gemm_astat(const unsigned short* __restrict__ Ahi, const unsigned short* __restrict__ Alo,
                     int M, const unsigned short* __restrict__ B, const float* __restrict__ bias,
                     unsigned short* __restrict__ Chi, unsigned short* __restrict__ Clo, int ldc) {
    constexpr int NT = BN / 16;
    constexpr int Ka = KF * 32;
    constexpr int SBLK = KF * 4;                 // KF even -> SBLK % 8 == 0
    __shared__ __align__(16) unsigned short sB[BN * SBLK * 8];
    const int tid = threadIdx.x;
    const int wave = tid >> 6, lane = tid & 63;
    const int quad = lane >> 4, l16 = lane & 15;
    const int rbase = blockIdx.x * 128;

    const int r0 = min(rbase + wave * 32 + l16, M - 1);
    const int r1 = min(rbase + wave * 32 + 16 + l16, M - 1);
    const unsigned short* pa0h = Ahi + (size_t)r0 * Ka + quad * 8;
    const unsigned short* pa1h = Ahi + (size_t)r1 * Ka + quad * 8;
    const unsigned short* pa0l = Alo + (size_t)r0 * Ka + quad * 8;
    const unsigned short* pa1l = Alo + (size_t)r1 * Ka + quad * 8;

    short8 afh[2][KF], afl[2][KF];
#pragma unroll
    for (int kf = 0; kf < KF; ++kf) {
        afh[0][kf] = *(const short8*)(pa0h + kf * 32);
        afh[1][kf] = *(const short8*)(pa1h + kf * 32);
        if (TERMS == 2) {
            afl[0][kf] = *(const short8*)(pa0l + kf * 32);
            afl[1][kf] = *(const short8*)(pa1l + kf * 32);
        }
    }

    for (int t = 0; t < NTILES; ++t) {
        const int cbase = t * BN;
        if (t) __syncthreads();
        for (int i = tid; i < BN * KF * 4; i += 256) {
            int n = i % BN, j = i / BN;
            *(uint4*)&sB[(n * SBLK + (j ^ (n & 7))) * 8] =
                *(const uint4*)(B + (size_t)(cbase + n) * Ka + j * 8);
        }
        __syncthreads();

        floatx4 acc[2][NT];
#pragma unroll
        for (int mt = 0; mt < 2; ++mt)
#pragma unroll
            for (int nt = 0; nt < NT; ++nt) acc[mt][nt] = (floatx4)0.0f;

#pragma unroll
        for (int kf = 0; kf < KF; ++kf) {
#pragma unroll
            for (int nt = 0; nt < NT; ++nt) {
                int jj = (kf * 4 + quad) ^ (l16 & 7);
                short8 b = *(const short8*)&sB[((nt * 16 + l16) * SBLK + jj) * 8];
                acc[0][nt] = mfma16(afh[0][kf], b, acc[0][nt]);
                if (TERMS == 2) acc[0][nt] = mfma16(afl[0][kf], b, acc[0][nt]);
                acc[1][nt] = mfma16(afh[1][kf], b, acc[1][nt]);
                if (TERMS == 2) acc[1][nt] = mfma16(afl[1][kf], b, acc[1][nt]);
            }
        }

        float bb[NT];
#pragma unroll
        for (int nt = 0; nt < NT; ++nt) bb[nt] = bias ? bias[cbase + nt * 16 + l16] : 0.f;
#pragma unroll
        for (int mt = 0; mt < 2; ++mt) {
#pragma unroll
            for (int reg = 0; reg < 4; ++reg) {
                int row = rbase + wave * 32 + mt * 16 + quad * 4 + reg;
                if (row < M) {
#pragma unroll
                    for (int nt = 0; nt < NT; ++nt) {
                        float v = acc[mt][nt][reg] + bb[nt];
                        if (EPI == 1) v = fmaxf(v, 0.f);
                        if (OUTMODE == 1) {
                            int c = cbase + nt * 16 + l16;
                            if (c < 192) {
                                Chi[(size_t)row * 192 + c] = f2bf(v);
                            } else {
                                int cc = c - 192;
                                int idx = (cc < 192) ? (cc * 2) : ((cc - 192) * 2 + 1);
                                Clo[(size_t)row * 384 + idx] = f2bf(v);
                            }
                        } else {
                            size_t off = (size_t)row * ldc + cbase + nt * 16 + l16;
                            if (DUAL) {
                                unsigned short hi, lo;
                                split_bf16(v, hi, lo);
                                Chi[off] = hi; Clo[off] = lo;
                            } else {
                                Chi[off] = f2bf(v);
                            }
                        }
                    }
                }
            }
        }
    }
}

// ---------------- edge attention: no-max softmax (shift-invariant; logits are O(3)) ---
__global__ __launch_bounds__(256)
void attn_kernel(const unsigned short* __restrict__ qB, const unsigned short* __restrict__ kvB,
                 const float* __restrict__ ea, const float* __restrict__ We_l,
                 const int2* __restrict__ csr2, const int* __restrict__ row_ptr,
                 unsigned short* __restrict__ msg_hi, unsigned short* __restrict__ msg_lo) {
    __shared__ float sWe[768];
    const int tid = threadIdx.x;
    for (int i = tid; i < 768; i += 256) sWe[i] = We_l[i];
    __syncthreads();

    const int lane = tid & 63;
    const int node = blockIdx.x * 4 + (tid >> 6);
    const int d0 = (lane >> 4) * 48 + (lane & 15) * 3;

    float W[4][3];
#pragma unroll
    for (int w = 0; w < 4; ++w) {
        W[w][0] = sWe[w * 192 + d0];
        W[w][1] = sWe[w * 192 + d0 + 1];
        W[w][2] = sWe[w * 192 + d0 + 2];
    }
    size_t qoff = (size_t)node * 192 + d0;
    float q0 = bf2f(qB[qoff]), q1 = bf2f(qB[qoff + 1]), q2 = bf2f(qB[qoff + 2]);
    float qe0 = q0 * W[0][0] + q1 * W[0][1] + q2 * W[0][2];
    float qe1 = q0 * W[1][0] + q1 * W[1][1] + q2 * W[1][2];
    float qe2 = q0 * W[2][0] + q1 * W[2][1] + q2 * W[2][2];
    float qe3 = q0 * W[3][0] + q1 * W[3][1] + q2 * W[3][2];
#pragma unroll
    for (int off = 1; off < 16; off <<= 1) {
        qe0 += __shfl_xor(qe0, off);
        qe1 += __shfl_xor(qe1, off);
        qe2 += __shfl_xor(qe2, off);
        qe3 += __shfl_xor(qe3, off);
    }

    const unsigned int* kv = (const unsigned int*)kvB;
    const float4* ea4 = (const float4*)ea;

    float den = 0.f;
    float v0 = 0.f, v1 = 0.f, v2 = 0.f;
    float wa0 = 0.f, wa1 = 0.f, wa2 = 0.f, wa3 = 0.f;
    const int beg = row_ptr[node], end = row_ptr[node + 1];
    int p = beg;
    for (; p + 3 < end; p += 4) {
        int2 seA = csr2[p], seB = csr2[p + 1], seC = csr2[p + 2], seD = csr2[p + 3];
        size_t bA = (size_t)seA.x * 192 + d0;
        size_t bB = (size_t)seB.x * 192 + d0;
        size_t bC = (size_t)seC.x * 192 + d0;
        size_t bD = (size_t)seD.x * 192 + d0;
        unsigned int uA0 = kv[bA], uA1 = kv[bA + 1], uA2 = kv[bA + 2];
        unsigned int uB0 = kv[bB], uB1 = kv[bB + 1], uB2 = kv[bB + 2];
        unsigned int uC0 = kv[bC], uC1 = kv[bC + 1], uC2 = kv[bC + 2];
        unsigned int uD0 = kv[bD], uD1 = kv[bD + 1], uD2 = kv[bD + 2];
        float4 wA = ea4[seA.y], wB = ea4[seB.y], wC = ea4[seC.y], wD = ea4[seD.y];
        float dA = q0 * bf2f((unsigned short)uA0) + q1 * bf2f((unsigned short)uA1) + q2 * bf2f((unsigned short)uA2);
        float dB = q0 * bf2f((unsigned short)uB0) + q1 * bf2f((unsigned short)uB1) + q2 * bf2f((unsigned short)uB2);
        float dC = q0 * bf2f((unsigned short)uC0) + q1 * bf2f((unsigned short)uC1) + q2 * bf2f((unsigned short)uC2);
        float dD = q0 * bf2f((unsigned short)uD0) + q1 * bf2f((unsigned short)uD1) + q2 * bf2f((unsigned short)uD2);
#pragma unroll
        for (int off = 1; off < 16; off <<= 1) {
            dA += __shfl_xor(dA, off);
            dB += __shfl_xor(dB, off);
            dC += __shfl_xor(dC, off);
            dD += __shfl_xor(dD, off);
        }
        float pA = __expf(dA + wA.x * qe0 + wA.y * qe1 + wA.z * qe2 + wA.w * qe3);
        float pB = __expf(dB + wB.x * qe0 + wB.y * qe1 + wB.z * qe2 + wB.w * qe3);
        float pC = __expf(dC + wC.x * qe0 + wC.y * qe1 + wC.z * qe2 + wC.w * qe3);
        float pD = __expf(dD + wD.x * qe0 + wD.y * qe1 + wD.z * qe2 + wD.w * qe3);
        den += pA + pB + pC + pD;
        v0 += pA * bf2f((unsigned short)(uA0 >> 16)) + pB * bf2f((unsigned short)(uB0 >> 16))
            + pC * bf2f((unsigned short)(uC0 >> 16)) + pD * bf2f((unsigned short)(uD0 >> 16));
        v1 += pA * bf2f((unsigned short)(uA1 >> 16)) + pB * bf2f((unsigned short)(uB1 >> 16))
            + pC * bf2f((unsigned short)(uC1 >> 16)) + pD * bf2f((unsigned short)(uD1 >> 16));
        v2 += pA * bf2f((unsigned short)(uA2 >> 16)) + pB * bf2f((unsigned short)(uB2 >> 16))
            + pC * bf2f((unsigned short)(uC2 >> 16)) + pD * bf2f((unsigned short)(uD2 >> 16));
        wa0 += pA * wA.x + pB * wB.x + pC * wC.x + pD * wD.x;
        wa1 += pA * wA.y + pB * wB.y + pC * wC.y + pD * wD.y;
        wa2 += pA * wA.z + pB * wB.z + pC * wC.z + pD * wD.z;
        wa3 += pA * wA.w + pB * wB.w + pC * wC.w + pD * wD.w;
    }
    for (; p < end; ++p) {
        int2 se = csr2[p];
        size_t b = (size_t)se.x * 192 + d0;
        unsigned int u0 = kv[b], u1 = kv[b + 1], u2 = kv[b + 2];
        float4 w = ea4[se.y];
        float d = q0 * bf2f((unsigned short)u0) + q1 * bf2f((unsigned short)u1)
                + q2 * bf2f((unsigned short)u2);
#pragma unroll
        for (int off = 1; off < 16; off <<= 1) d += __shfl_xor(d, off);
        float pe = __expf(d + w.x * qe0 + w.y * qe1 + w.z * qe2 + w.w * qe3);
        den += pe;
        v0 += pe * bf2f((unsigned short)(u0 >> 16));
        v1 += pe * bf2f((unsigned short)(u1 >> 16));
        v2 += pe * bf2f((unsigned short)(u2 >> 16));
        wa0 += pe * w.x;
        wa1 += pe * w.y;
        wa2 += pe * w.z;
        wa3 += pe * w.w;
    }
    float inv = 1.f / (den + 1e-16f);
    float m0 = (v0 + wa0 * W[0][0] + wa1 * W[1][0] + wa2 * W[2][0] + wa3 * W[3][0]) * inv;
    float m1 = (v1 + wa0 * W[0][1] + wa1 * W[1][1] + wa2 * W[2][1] + wa3 * W[3][1]) * inv;
    float m2 = (v2 + wa0 * W[0][2] + wa1 * W[1][2] + wa2 * W[2][2] + wa3 * W[3][2]) * inv;
    size_t ob = (size_t)node * 192 + d0;
    unsigned short hi, lo;
    split_bf16(m0, hi, lo); msg_hi[ob] = hi;     msg_lo[ob] = lo;
    split_bf16(m1, hi, lo); msg_hi[ob + 1] = hi; msg_lo[ob + 1] = lo;
    split_bf16(m2, hi, lo); msg_hi[ob + 2] = hi; msg_lo[ob + 2] = lo;
}

// ---------------- edge head: register A-fragments, single-term, swizzled sW -----------
__global__ __launch_bounds__(256, 2)
void edge_head_kernel(const unsigned short* __restrict__ hsd, const float* __restrict__ ea,
                      const int* __restrict__ src, const int* __restrict__ dst,
                      const float* __restrict__ W1e, const float* __restrict__ b1,
                      const unsigned short* __restrict__ W2hi,
                      const float* __restrict__ b2, const float* __restrict__ W3,
                      const float* __restrict__ b3, float* __restrict__ out) {
    __shared__ __align__(16) unsigned short sW[96 * 192];   // SBLK=24 blocks, swizzled
    __shared__ __align__(16) float sWe1[768];
    __shared__ __align__(16) float sB1[192];
    const int tid = threadIdx.x;
    const int wave = tid >> 6, lane = tid & 63;
    const int quad = lane >> 4, l16 = lane & 15;
    const int ebase = blockIdx.x * 64;

    for (int i = tid; i < 768; i += 256) sWe1[i] = W1e[i];
    if (tid < 192) sB1[tid] = b1[tid];
    for (int i = tid; i < 96 * 24; i += 256) {
        int n = i % 96, j = i / 96;
        *(uint4*)&sW[(n * 24 + (j ^ (n & 7))) * 8] = *(const uint4*)(W2hi + (size_t)n * 192 + j * 8);
    }

    const int e = ebase + wave * 16 + l16;        // this lane's edge
    const int s = src[e], d = dst[e];
    const float4 eav = *(const float4*)(ea + (size_t)e * 4);
    const unsigned short* hs_p = hsd + (size_t)s * 384 + quad * 8;
    const unsigned short* hd_p = hsd + (size_t)d * 384 + 192 + quad * 8;

    floatx4 acc[6];
#pragma unroll
    for (int nt = 0; nt < 6; ++nt) acc[nt] = (floatx4)0.0f;
    __syncthreads();

    ushort8 hs_c = *(const ushort8*)hs_p;
    ushort8 hd_c = *(const ushort8*)hd_p;
#pragma unroll
    for (int kc = 0; kc < 192; kc += 32) {
        ushort8 hs_n = hs_c, hd_n = hd_c;
        if (kc + 32 < 192) {
            hs_n = *(const ushort8*)(hs_p + kc + 32);
            hd_n = *(const ushort8*)(hd_p + kc + 32);
        }
        const int c0 = kc + quad * 8;
        float wb1[8], w0v[8], w1v[8], w2v[8], w3v[8];
        *(float4*)&wb1[0] = *(const float4*)&sB1[c0];
        *(float4*)&wb1[4] = *(const float4*)&sB1[c0 + 4];
        *(float4*)&w0v[0] = *(const float4*)&sWe1[c0];
        *(float4*)&w0v[4] = *(const float4*)&sWe1[c0 + 4];
        *(float4*)&w1v[0] = *(const float4*)&sWe1[192 + c0];
        *(float4*)&w1v[4] = *(const float4*)&sWe1[192 + c0 + 4];
        *(float4*)&w2v[0] = *(const float4*)&sWe1[384 + c0];
        *(float4*)&w2v[4] = *(const float4*)&sWe1[384 + c0 + 4];
        *(float4*)&w3v[0] = *(const float4*)&sWe1[576 + c0];
        *(float4*)&w3v[4] = *(const float4*)&sWe1[576 + c0 + 4];
        ushort8 ah;
#pragma unroll
        for (int j = 0; j < 8; ++j) {
            float ce = wb1[j] + eav.x * w0v[j] + eav.y * w1v[j]
                     + eav.z * w2v[j] + eav.w * w3v[j];
            float v = fmaxf(bf2f(hs_c[j]) + bf2f(hd_c[j]) + ce, 0.f);
            ah[j] = f2bf(v);
        }
        short8 ahs = *(short8*)&ah;
        const int jbase = kc / 8;
#pragma unroll
        for (int nt = 0; nt < 6; ++nt) {
            int jj = (jbase + quad) ^ (l16 & 7);
            short8 bh = *(const short8*)&sW[((nt * 16 + l16) * 24 + jj) * 8];
            acc[nt] = mfma16(ahs, bh, acc[nt]);
        }
        hs_c = hs_n; hd_c = hd_n;
    }

    float w3[6], bb2[6];
#pragma unroll
    for (int nt = 0; nt < 6; ++nt) {
        int col = nt * 16 + l16;
        w3[nt] = W3[col];
        bb2[nt] = b2[col];
    }
    float b3v = b3[0];
#pragma unroll
    for (int reg = 0; reg < 4; ++reg) {
        float sacc = 0.f;
#pragma unroll
        for (int nt = 0; nt < 6; ++nt) {
            float z = fmaxf(acc[nt][reg] + bb2[nt], 0.f);
            sacc = fmaf(z, w3[nt], sacc);
        }
#pragma unroll
        for (int off = 1; off < 16; off <<= 1) sacc += __shfl_xor(sacc, off);
        if (l16 == 0) out[ebase + wave * 16 + quad * 4 + reg] = sacc + b3v;
    }
}

extern "C" void kernel_launch(void* const* d_in, const int* in_sizes, int n_in,
                              void* d_out, int out_size, void* d_ws, size_t ws_size,
                              hipStream_t stream) {
    const float* x     = (const float*)d_in[0];
    const int*   eidx  = (const int*)d_in[1];
    const float* ea    = (const float*)d_in[2];
    const int*   batch = (const int*)d_in[3];
    const int*   gptr  = (const int*)d_in[4];
    const int*   tgid  = (const int*)d_in[5];
    const float* gp    = (const float*)d_in[6];
    const float* sp    = (const float*)d_in[7];
    const float* epp   = (const float*)d_in[8];
    const float* W_in  = (const float*)d_in[9];
    const float* b_in  = (const float*)d_in[10];
    const float* Wq    = (const float*)d_in[11];
    const float* Wk    = (const float*)d_in[12];
    const float* Wv    = (const float*)d_in[13];
    const float* We    = (const float*)d_in[14];
    const float* Wo    = (const float*)d_in[15];
    const float* bo    = (const float*)d_in[16];
    const float* ln1g  = (const float*)d_in[17];
    const float* ln1b  = (const float*)d_in[18];
    const float* Wf1   = (const float*)d_in[19];
    const float* bf1   = (const float*)d_in[20];
    const float* Wf2   = (const float*)d_in[21];
    const float* bf2   = (const float*)d_in[22];
    const float* ln2g  = (const float*)d_in[23];
    const float* ln2b  = (const float*)d_in[24];
    const float* We1   = (const float*)d_in[25];
    const float* be1   = (const float*)d_in[26];
    const float* We2   = (const float*)d_in[27];
    const float* be2   = (const float*)d_in[28];
    const float* We3   = (const float*)d_in[29];
    const float* be3   = (const float*)d_in[30];
    const int* src = eidx;
    const int* dst = eidx + N_EDGES;

    unsigned short* ub = (unsigned short*)d_ws;
    unsigned short* featH = ub;                  // 40000*32
    unsigned short* featL = ub + 1280000;
    unsigned short* hH    = ub + 2560000;        // 40000*192 each
    unsigned short* hL    = ub + 10240000;
    unsigned short* htH   = ub + 17920000;
    unsigned short* htL   = ub + 25600000;
    unsigned short* msgH  = ub + 33280000;
    unsigned short* msgL  = ub + 40960000;
    unsigned short* rbuf  = ub + 48640000;       // 40000*768 region
    unsigned short* qB    = rbuf;                // 40000*192
    unsigned short* kvB   = rbuf + 7680000;      // 40000*384 interleaved k/v
    unsigned short* ffH   = rbuf;                // 40000*384 (after attn)
    unsigned short* ffL   = rbuf + 15360000;
    unsigned short* hsdB  = rbuf;                // 40000*384
    unsigned short* wb    = ub + 79360000;       // WTOT
    int* ib   = (int*)(ub + 80343040);
    int* cnt  = ib;
    int* rowp = ib + 40000;
    int* curs = ib + 80004;
    int2* csr2 = (int2*)(ib + 120004);
    int* bsum  = ib + 920004;
    int* boffs = ib + 920044;

    hipMemsetAsync(cnt, 0, N_NODES * sizeof(int), stream);
    count_kernel<<<1563, 256, 0, stream>>>(dst, cnt, N_EDGES);
    scan1_kernel<<<40, 1024, 0, stream>>>(cnt, rowp, bsum, N_NODES);
    scan2_kernel<<<1, 64, 0, stream>>>(bsum, boffs, rowp, 40, N_NODES);
    scan3_kernel<<<40, 1024, 0, stream>>>(rowp, curs, boffs, N_NODES);
    scatter_kernel<<<1563, 256, 0, stream>>>(src, dst, curs, csr2, N_EDGES);
    feat_kernel<<<5000, 256, 0, stream>>>(x, batch, gptr, tgid, gp, sp, epp, featH, featL, N_NODES);
    prep_kernel<<<3840, 256, 0, stream>>>(W_in, Wq, Wk, Wv, Wo, Wf1, Wf2, We1, We2, wb);

    dim3 blk(256);
    // input projection: feat[40000, K=32 planes] @ W_in -> h planes (chunked path)
    mfma_gemm<0, 1, 96, 32, 2><<<dim3(313, 2), blk, 0, stream>>>(featH, featL, N_NODES, 32,
        wb + WOFF_WIN, b_in, nullptr, nullptr, nullptr, nullptr, hH, hL, 192);

    for (int l = 0; l < 3; ++l) {
        const unsigned short* wq = wb + WOFF_QKV + l * 110592;
        // fused qkv, A-stationary: 6 tiles of 96; q -> qB, k/v -> kvB interleaved
        mfma_gemm_astat<0, 0, 96, 6, 1, 6, 1><<<313, blk, 0, stream>>>(hH, hL, N_NODES,
            wq, nullptr, qB, kvB, 0);
        attn_kernel<<<10000, blk, 0, stream>>>(qB, kvB, ea, We + l * 768, csr2, rowp, msgH, msgL);
        mfma_gemm<2, 1, 192, 96, 2><<<dim3(313, 1), blk, 0, stream>>>(msgH, msgL, N_NODES, 192,
            wb + WOFF_WO + l * 36864, bo + l * 192, hH, hL, ln1g + l * 192, ln1b + l * 192,
            htH, htL, 192);
        mfma_gemm_astat<1, 1, 96, 4, 2, 6, 0><<<313, blk, 0, stream>>>(htH, htL, N_NODES,
            wb + WOFF_WF1 + l * 73728, bf1 + l * 384, ffH, ffL, 384);
        mfma_gemm<2, 1, 192, 96, 2><<<dim3(313, 1), blk, 0, stream>>>(ffH, ffL, N_NODES, 384,
            wb + WOFF_WF2 + l * 73728, bf2 + l * 192, htH, htL, ln2g + l * 192, ln2b + l * 192,
            hH, hL, 192);
    }

    // edge head pre-projections, A-stationary: [Hs|Hd] -> hsdB bf16 [N,384]
    mfma_gemm_astat<0, 0, 96, 4, 2, 6, 0><<<313, blk, 0, stream>>>(hH, hL, N_NODES,
        wb + WOFF_HSD, nullptr, hsdB, nullptr, 384);
    edge_head_kernel<<<6250, blk, 0, stream>>>(hsdB, ea, src, dst,
        We1 + 384 * 192, be1, wb + WOFF_WE2, be2, We3, be3, (float*)d_out);
}

// Round 8
// 866.609 us; speedup vs baseline: 1.3935x; 1.0499x over previous
//
#include <hip/hip_runtime.h>
#include <hip/hip_bf16.h>
#include <math.h>

#define N_NODES 40000
#define N_EDGES 400000
#define GCLIP 511

using short8  = __attribute__((ext_vector_type(8))) short;
using ushort8 = __attribute__((ext_vector_type(8))) unsigned short;
using floatx4 = __attribute__((ext_vector_type(4))) float;

__device__ __forceinline__ void split_bf16(float v, unsigned short& hi, unsigned short& lo) {
    __hip_bfloat16 h = __float2bfloat16(v);
    float r = v - __bfloat162float(h);
    __hip_bfloat16 l = __float2bfloat16(r);
    hi = *(unsigned short*)&h;
    lo = *(unsigned short*)&l;
}
__device__ __forceinline__ unsigned short f2bf(float f) {
    __hip_bfloat16 h = __float2bfloat16(f);
    return *(unsigned short*)&h;
}
__device__ __forceinline__ float bf2f(unsigned short u) {
    __hip_bfloat16 h = *(__hip_bfloat16*)&u;
    return __bfloat162float(h);
}
__device__ __forceinline__ floatx4 mfma16(short8 a, short8 b, floatx4 c) {
    return __builtin_amdgcn_mfma_f32_16x16x32_bf16(a, b, c, 0, 0, 0);
}

// ---------------- CSR build ----------------
__global__ void count_kernel(const int* __restrict__ dst, int* __restrict__ cnt, int E) {
    int e = blockIdx.x * 256 + threadIdx.x;
    if (e < E) atomicAdd(&cnt[dst[e]], 1);
}

__global__ void scan1_kernel(const int* __restrict__ cnt, int* __restrict__ rowp,
                             int* __restrict__ bsum, int n) {
    __shared__ int wsum[16];
    __shared__ int woff[16];
    int tid = threadIdx.x, wave = tid >> 6, lane = tid & 63;
    int i = blockIdx.x * 1024 + tid;
    int v = (i < n) ? cnt[i] : 0;
    int x = v;
    for (int off = 1; off < 64; off <<= 1) {
        int t = __shfl_up(x, off);
        if (lane >= off) x += t;
    }
    if (lane == 63) wsum[wave] = x;
    __syncthreads();
    if (wave == 0 && lane < 16) {
        int s = wsum[lane];
        for (int off = 1; off < 16; off <<= 1) {
            int t = __shfl_up(s, off);
            if (lane >= off) s += t;
        }
        woff[lane] = s;
    }
    __syncthreads();
    int incl = x + ((wave == 0) ? 0 : woff[wave - 1]);
    if (i < n) rowp[i] = incl - v;
    if (tid == 1023) bsum[blockIdx.x] = incl;
}

__global__ void scan2_kernel(const int* __restrict__ bsum, int* __restrict__ boffs,
                             int* __restrict__ rowp, int nb, int n) {
    int lane = threadIdx.x;
    int v = (lane < nb) ? bsum[lane] : 0;
    int x = v;
    for (int off = 1; off < 64; off <<= 1) {
        int t = __shfl_up(x, off);
        if (lane >= off) x += t;
    }
    if (lane < nb) boffs[lane] = x - v;
    if (lane == nb - 1) rowp[n] = x;
}

__global__ void scan3_kernel(int* __restrict__ rowp, int* __restrict__ curs,
                             const int* __restrict__ boffs, int n) {
    int i = blockIdx.x * 1024 + threadIdx.x;
    if (i < n) {
        int v = rowp[i] + boffs[blockIdx.x];
        rowp[i] = v;
        curs[i] = v;
    }
}

__global__ void scatter_kernel(const int* __restrict__ src, const int* __restrict__ dst,
                               int* __restrict__ cursor, int2* __restrict__ csr2, int E) {
    int e = blockIdx.x * 256 + threadIdx.x;
    if (e < E) {
        int pos = atomicAdd(&cursor[dst[e]], 1);
        csr2[pos] = make_int2(src[e], e);
    }
}

// ---------------- feature build -> bf16 hi/lo planes [N][32] (cols 16..31 zero) -------
__global__ void feat_kernel(const float* __restrict__ x, const int* __restrict__ batch,
                            const int* __restrict__ gptr, const int* __restrict__ tgid,
                            const float* __restrict__ gp, const float* __restrict__ sp,
                            const float* __restrict__ ep,
                            unsigned short* __restrict__ fhi, unsigned short* __restrict__ flo,
                            int n) {
    int idx = blockIdx.x * 256 + threadIdx.x;
    if (idx >= n * 32) return;
    int node = idx >> 5, c = idx & 31;
    float v = 0.f;
    if (c < 4) {
        v = x[node * 4 + c];
    } else if (c < 7) {
        int gid = gptr[batch[node]] + tgid[node];
        gid = min(max(gid, 0), GCLIP);
        v = gp[gid * 3 + (c - 4)];
    } else if (c < 10) {
        v = sp[node * 3 + (c - 7)];
    } else if (c < 16) {
        int gid = gptr[batch[node]] + tgid[node];
        gid = min(max(gid, 0), GCLIP);
        v = ep[gid * 6 + (c - 10)];
    }
    unsigned short hi, lo;
    split_bf16(v, hi, lo);
    fhi[idx] = hi;
    flo[idx] = lo;
}

// ---------------- weight prep: transpose to [Nrows][Ka] bf16 (hi only) ----------------
#define WOFF_WIN 0
#define WOFF_QKV 6144
#define WOFF_WO  337920
#define WOFF_WF1 448512
#define WOFF_WF2 669696
#define WOFF_HSD 890880
#define WOFF_WE2 964608
#define WTOT     983040

__global__ void prep_kernel(const float* __restrict__ W_in, const float* __restrict__ Wq,
                            const float* __restrict__ Wk, const float* __restrict__ Wv,
                            const float* __restrict__ Wo, const float* __restrict__ Wf1,
                            const float* __restrict__ Wf2, const float* __restrict__ We1,
                            const float* __restrict__ We2, unsigned short* __restrict__ wb) {
    int idx = blockIdx.x * 256 + threadIdx.x;
    if (idx >= WTOT) return;
    float val;
    if (idx < WOFF_QKV) {                       // W_in^T [192][32], K=16 padded
        int n = idx / 32, k = idx % 32;
        val = (k < 16) ? W_in[k * 192 + n] : 0.f;
    } else if (idx < WOFF_WO) {                 // Wqkv^T [576][192] x3; q rows pre-scaled
        int r = idx - WOFF_QKV; int l = r / 110592; r %= 110592;
        int n = r / 192, k = r % 192;
        const float* s = (n < 192) ? Wq : (n < 384 ? Wk : Wv);
        val = s[l * 36864 + k * 192 + (n % 192)];
        if (n < 192) val *= 0.14433756729740643f;   // 1/sqrt(48) folded into Wq
    } else if (idx < WOFF_WF1) {                // Wo^T [192][192] x3
        int r = idx - WOFF_WO; int l = r / 36864; r %= 36864;
        int n = r / 192, k = r % 192;
        val = Wo[l * 36864 + k * 192 + n];
    } else if (idx < WOFF_WF2) {                // Wf1^T [384][192] x3
        int r = idx - WOFF_WF1; int l = r / 73728; r %= 73728;
        int n = r / 192, k = r % 192;
        val = Wf1[l * 73728 + k * 384 + n];
    } else if (idx < WOFF_HSD) {                // Wf2^T [192][384] x3
        int r = idx - WOFF_WF2; int l = r / 73728; r %= 73728;
        int n = r / 384, k = r % 384;
        val = Wf2[l * 73728 + k * 192 + n];
    } else if (idx < WOFF_WE2) {                // [Hs|Hd]^T [384][192]
        int r = idx - WOFF_HSD;
        int n = r / 192, k = r % 192;
        val = (n < 192) ? We1[k * 192 + n] : We1[(192 + k) * 192 + (n - 192)];
    } else {                                    // We2^T [96][192]
        int r = idx - WOFF_WE2;
        int n = r / 192, k = r % 192;
        val = We2[k * 96 + n];
    }
    wb[idx] = f2bf(val);
}

// LDS tile layout: row n holds k-block j (8 ushorts) at slot (j ^ (n&7)); row stride
// SBLK % 8 == 0 blocks -> stride 0 mod 32 dwords -> conflict-free fragment reads.

// ---------------- chunked MFMA GEMM (input proj / wo / ff2) ---------------------------
template <int EPI, int DUAL, int BN, int KCH, int TERMS>
__global__ __launch_bounds__(256, 2)
void mfma_gemm(const unsigned short* __restrict__ Ahi, const unsigned short* __restrict__ Alo,
               int M, int Ka,
               const unsigned short* __restrict__ B, const float* __restrict__ bias,
               const unsigned short* __restrict__ Rhi, const unsigned short* __restrict__ Rlo,
               const float* __restrict__ lng, const float* __restrict__ lnb,
               unsigned short* __restrict__ Chi, unsigned short* __restrict__ Clo, int ldc) {
    constexpr int NT = BN / 16;
    constexpr int JB = KCH / 8;
    constexpr int SBLK = ((JB + 7) / 8) * 8;
    __shared__ __align__(16) unsigned short sB[BN * SBLK * 8];
    const int tid = threadIdx.x;
    const int wave = tid >> 6, lane = tid & 63;
    const int quad = lane >> 4, l16 = lane & 15;
    const int rbase = blockIdx.x * 128;
    const int cbase = blockIdx.y * BN;

    floatx4 acc[2][NT];
#pragma unroll
    for (int mt = 0; mt < 2; ++mt)
#pragma unroll
        for (int nt = 0; nt < NT; ++nt) acc[mt][nt] = (floatx4)0.0f;

    const int r0 = min(rbase + wave * 32 + l16, M - 1);
    const int r1 = min(rbase + wave * 32 + 16 + l16, M - 1);
    const unsigned short* pa0h = Ahi + (size_t)r0 * Ka + quad * 8;
    const unsigned short* pa1h = Ahi + (size_t)r1 * Ka + quad * 8;
    const unsigned short* pa0l = Alo + (size_t)r0 * Ka + quad * 8;
    const unsigned short* pa1l = Alo + (size_t)r1 * Ka + quad * 8;

    for (int kb = 0; kb < Ka; kb += KCH) {
        if (kb) __syncthreads();
        for (int i = tid; i < BN * JB; i += 256) {
            int n = i % BN, j = i / BN;
            *(uint4*)&sB[(n * SBLK + (j ^ (n & 7))) * 8] =
                *(const uint4*)(B + (size_t)(cbase + n) * Ka + kb + j * 8);
        }
        __syncthreads();
        short8 ch0 = *(const short8*)(pa0h + kb);
        short8 ch1 = *(const short8*)(pa1h + kb);
        short8 cl0, cl1;
        if (TERMS == 2) {
            cl0 = *(const short8*)(pa0l + kb);
            cl1 = *(const short8*)(pa1l + kb);
        }
#pragma unroll
        for (int kc = 0; kc < KCH; kc += 32) {
            short8 nh0 = ch0, nh1 = ch1, nl0 = ch0, nl1 = ch1;
            if (kc + 32 < KCH) {
                nh0 = *(const short8*)(pa0h + kb + kc + 32);
                nh1 = *(const short8*)(pa1h + kb + kc + 32);
                if (TERMS == 2) {
                    nl0 = *(const short8*)(pa0l + kb + kc + 32);
                    nl1 = *(const short8*)(pa1l + kb + kc + 32);
                }
            }
            const int jbase = kc / 8;
#pragma unroll
            for (int nt = 0; nt < NT; ++nt) {
                int jj = (jbase + quad) ^ (l16 & 7);
                short8 b = *(const short8*)&sB[((nt * 16 + l16) * SBLK + jj) * 8];
                acc[0][nt] = mfma16(ch0, b, acc[0][nt]);
                if (TERMS == 2) acc[0][nt] = mfma16(cl0, b, acc[0][nt]);
                acc[1][nt] = mfma16(ch1, b, acc[1][nt]);
                if (TERMS == 2) acc[1][nt] = mfma16(cl1, b, acc[1][nt]);
            }
            ch0 = nh0; ch1 = nh1;
            if (TERMS == 2) { cl0 = nl0; cl1 = nl1; }
        }
    }

    float bb[NT], gg[NT], be[NT];
#pragma unroll
    for (int nt = 0; nt < NT; ++nt) {
        int colg = cbase + nt * 16 + l16;
        bb[nt] = bias ? bias[colg] : 0.f;
        if (EPI == 2) { gg[nt] = lng[colg]; be[nt] = lnb[colg]; }
    }
#pragma unroll
    for (int mt = 0; mt < 2; ++mt) {
#pragma unroll
        for (int reg = 0; reg < 4; ++reg) {
            int row = rbase + wave * 32 + mt * 16 + quad * 4 + reg;
            if (EPI == 2) {
                int rr = min(row, M - 1);
                float v[NT], s = 0.f, q = 0.f;
#pragma unroll
                for (int nt = 0; nt < NT; ++nt) {
                    size_t off = (size_t)rr * 192 + nt * 16 + l16;
                    float resid = bf2f(Rhi[off]) + bf2f(Rlo[off]);
                    v[nt] = acc[mt][nt][reg] + bb[nt] + resid;
                    s += v[nt]; q += v[nt] * v[nt];
                }
#pragma unroll
                for (int off = 1; off < 16; off <<= 1) {
                    s += __shfl_xor(s, off);
                    q += __shfl_xor(q, off);
                }
                float mean = s * (1.f / 192.f);
                float var = q * (1.f / 192.f) - mean * mean;
                float rs = rsqrtf(var + 1e-5f);
                if (row < M) {
#pragma unroll
                    for (int nt = 0; nt < NT; ++nt) {
                        float r = (v[nt] - mean) * rs * gg[nt] + be[nt];
                        unsigned short hi, lo;
                        split_bf16(r, hi, lo);
                        size_t off = (size_t)row * 192 + nt * 16 + l16;
                        Chi[off] = hi; Clo[off] = lo;
                    }
                }
            } else if (row < M) {
#pragma unroll
                for (int nt = 0; nt < NT; ++nt) {
                    float v = acc[mt][nt][reg] + bb[nt];
                    if (EPI == 1) v = fmaxf(v, 0.f);
                    size_t off = (size_t)row * ldc + cbase + nt * 16 + l16;
                    if (DUAL) {
                        unsigned short hi, lo;
                        split_bf16(v, hi, lo);
                        Chi[off] = hi; Clo[off] = lo;
                    } else {
                        Chi[off] = f2bf(v);
                    }
                }
            }
        }
    }
}

// ---------------- A-stationary MFMA GEMM (qkv / ff1 / hsd) ----------------------------
template <int EPI, int DUAL, int BN, int NTILES, int TERMS, int KF, int OUTMODE>
__global__ __launch_bounds__(256, 2)
void mfma_gemm_astat(const unsigned short* __restrict__ Ahi, const unsigned short* __restrict__ Alo,
                     int M, const unsigned short* __restrict__ B, const float* __restrict__ bias,
                     unsigned short* __restrict__ Chi, unsigned short* __restrict__ Clo, int ldc) {
    constexpr int NT = BN / 16;
    constexpr int Ka = KF * 32;
    constexpr int SBLK = KF * 4;
    __shared__ __align__(16) unsigned short sB[BN * SBLK * 8];
    const int tid = threadIdx.x;
    const int wave = tid >> 6, lane = tid & 63;
    const int quad = lane >> 4, l16 = lane & 15;
    const int rbase = blockIdx.x * 128;

    const int r0 = min(rbase + wave * 32 + l16, M - 1);
    const int r1 = min(rbase + wave * 32 + 16 + l16, M - 1);
    const unsigned short* pa0h = Ahi + (size_t)r0 * Ka + quad * 8;
    const unsigned short* pa1h = Ahi + (size_t)r1 * Ka + quad * 8;
    const unsigned short* pa0l = Alo + (size_t)r0 * Ka + quad * 8;
    const unsigned short* pa1l = Alo + (size_t)r1 * Ka + quad * 8;

    short8 afh[2][KF], afl[2][KF];
#pragma unroll
    for (int kf = 0; kf < KF; ++kf) {
        afh[0][kf] = *(const short8*)(pa0h + kf * 32);
        afh[1][kf] = *(const short8*)(pa1h + kf * 32);
        if (TERMS == 2) {
            afl[0][kf] = *(const short8*)(pa0l + kf * 32);
            afl[1][kf] = *(const short8*)(pa1l + kf * 32);
        }
    }

    for (int t = 0; t < NTILES; ++t) {
        const int cbase = t * BN;
        if (t) __syncthreads();
        for (int i = tid; i < BN * KF * 4; i += 256) {
            int n = i % BN, j = i / BN;
            *(uint4*)&sB[(n * SBLK + (j ^ (n & 7))) * 8] =
                *(const uint4*)(B + (size_t)(cbase + n) * Ka + j * 8);
        }
        __syncthreads();

        floatx4 acc[2][NT];
#pragma unroll
        for (int mt = 0; mt < 2; ++mt)
#pragma unroll
            for (int nt = 0; nt < NT; ++nt) acc[mt][nt] = (floatx4)0.0f;

#pragma unroll
        for (int kf = 0; kf < KF; ++kf) {
#pragma unroll
            for (int nt = 0; nt < NT; ++nt) {
                int jj = (kf * 4 + quad) ^ (l16 & 7);
                short8 b = *(const short8*)&sB[((nt * 16 + l16) * SBLK + jj) * 8];
                acc[0][nt] = mfma16(afh[0][kf], b, acc[0][nt]);
                if (TERMS == 2) acc[0][nt] = mfma16(afl[0][kf], b, acc[0][nt]);
                acc[1][nt] = mfma16(afh[1][kf], b, acc[1][nt]);
                if (TERMS == 2) acc[1][nt] = mfma16(afl[1][kf], b, acc[1][nt]);
            }
        }

        float bb[NT];
#pragma unroll
        for (int nt = 0; nt < NT; ++nt) bb[nt] = bias ? bias[cbase + nt * 16 + l16] : 0.f;
#pragma unroll
        for (int mt = 0; mt < 2; ++mt) {
#pragma unroll
            for (int reg = 0; reg < 4; ++reg) {
                int row = rbase + wave * 32 + mt * 16 + quad * 4 + reg;
                if (row < M) {
#pragma unroll
                    for (int nt = 0; nt < NT; ++nt) {
                        float v = acc[mt][nt][reg] + bb[nt];
                        if (EPI == 1) v = fmaxf(v, 0.f);
                        if (OUTMODE == 1) {
                            int c = cbase + nt * 16 + l16;
                            if (c < 192) {
                                Chi[(size_t)row * 192 + c] = f2bf(v);
                            } else {
                                int cc = c - 192;
                                int idx = (cc < 192) ? (cc * 2) : ((cc - 192) * 2 + 1);
                                Clo[(size_t)row * 384 + idx] = f2bf(v);
                            }
                        } else {
                            size_t off = (size_t)row * ldc + cbase + nt * 16 + l16;
                            if (DUAL) {
                                unsigned short hi, lo;
                                split_bf16(v, hi, lo);
                                Chi[off] = hi; Clo[off] = lo;
                            } else {
                                Chi[off] = f2bf(v);
                            }
                        }
                    }
                }
            }
        }
    }
}

// ---------------- edge attention (round-6 layout, msgH-only output) -------------------
// no-max softmax (exact, shift-invariant; logits O(3)); 4-edge unroll.
__global__ __launch_bounds__(256)
void attn_kernel(const unsigned short* __restrict__ qB, const unsigned short* __restrict__ kvB,
                 const float* __restrict__ ea, const float* __restrict__ We_l,
                 const int2* __restrict__ csr2, const int* __restrict__ row_ptr,
                 unsigned short* __restrict__ msg_hi) {
    __shared__ float sWe[768];
    const int tid = threadIdx.x;
    for (int i = tid; i < 768; i += 256) sWe[i] = We_l[i];
    __syncthreads();

    const int lane = tid & 63;
    const int node = blockIdx.x * 4 + (tid >> 6);
    const int d0 = (lane >> 4) * 48 + (lane & 15) * 3;

    float W[4][3];
#pragma unroll
    for (int w = 0; w < 4; ++w) {
        W[w][0] = sWe[w * 192 + d0];
        W[w][1] = sWe[w * 192 + d0 + 1];
        W[w][2] = sWe[w * 192 + d0 + 2];
    }
    size_t qoff = (size_t)node * 192 + d0;
    float q0 = bf2f(qB[qoff]), q1 = bf2f(qB[qoff + 1]), q2 = bf2f(qB[qoff + 2]);
    float qe0 = q0 * W[0][0] + q1 * W[0][1] + q2 * W[0][2];
    float qe1 = q0 * W[1][0] + q1 * W[1][1] + q2 * W[1][2];
    float qe2 = q0 * W[2][0] + q1 * W[2][1] + q2 * W[2][2];
    float qe3 = q0 * W[3][0] + q1 * W[3][1] + q2 * W[3][2];
#pragma unroll
    for (int off = 1; off < 16; off <<= 1) {
        qe0 += __shfl_xor(qe0, off);
        qe1 += __shfl_xor(qe1, off);
        qe2 += __shfl_xor(qe2, off);
        qe3 += __shfl_xor(qe3, off);
    }

    const unsigned int* kv = (const unsigned int*)kvB;
    const float4* ea4 = (const float4*)ea;

    float den = 0.f;
    float v0 = 0.f, v1 = 0.f, v2 = 0.f;
    float wa0 = 0.f, wa1 = 0.f, wa2 = 0.f, wa3 = 0.f;
    const int beg = row_ptr[node], end = row_ptr[node + 1];
    int p = beg;
    for (; p + 3 < end; p += 4) {
        int2 seA = csr2[p], seB = csr2[p + 1], seC = csr2[p + 2], seD = csr2[p + 3];
        size_t bA = (size_t)seA.x * 192 + d0;
        size_t bB = (size_t)seB.x * 192 + d0;
        size_t bC = (size_t)seC.x * 192 + d0;
        size_t bD = (size_t)seD.x * 192 + d0;
        unsigned int uA0 = kv[bA], uA1 = kv[bA + 1], uA2 = kv[bA + 2];
        unsigned int uB0 = kv[bB], uB1 = kv[bB + 1], uB2 = kv[bB + 2];
        unsigned int uC0 = kv[bC], uC1 = kv[bC + 1], uC2 = kv[bC + 2];
        unsigned int uD0 = kv[bD], uD1 = kv[bD + 1], uD2 = kv[bD + 2];
        float4 wA = ea4[seA.y], wB = ea4[seB.y], wC = ea4[seC.y], wD = ea4[seD.y];
        float dA = q0 * bf2f((unsigned short)uA0) + q1 * bf2f((unsigned short)uA1) + q2 * bf2f((unsigned short)uA2);
        float dB = q0 * bf2f((unsigned short)uB0) + q1 * bf2f((unsigned short)uB1) + q2 * bf2f((unsigned short)uB2);
        float dC = q0 * bf2f((unsigned short)uC0) + q1 * bf2f((unsigned short)uC1) + q2 * bf2f((unsigned short)uC2);
        float dD = q0 * bf2f((unsigned short)uD0) + q1 * bf2f((unsigned short)uD1) + q2 * bf2f((unsigned short)uD2);
#pragma unroll
        for (int off = 1; off < 16; off <<= 1) {
            dA += __shfl_xor(dA, off);
            dB += __shfl_xor(dB, off);
            dC += __shfl_xor(dC, off);
            dD += __shfl_xor(dD, off);
        }
        float pA = __expf(dA + wA.x * qe0 + wA.y * qe1 + wA.z * qe2 + wA.w * qe3);
        float pB = __expf(dB + wB.x * qe0 + wB.y * qe1 + wB.z * qe2 + wB.w * qe3);
        float pC = __expf(dC + wC.x * qe0 + wC.y * qe1 + wC.z * qe2 + wC.w * qe3);
        float pD = __expf(dD + wD.x * qe0 + wD.y * qe1 + wD.z * qe2 + wD.w * qe3);
        den += pA + pB + pC + pD;
        v0 += pA * bf2f((unsigned short)(uA0 >> 16)) + pB * bf2f((unsigned short)(uB0 >> 16))
            + pC * bf2f((unsigned short)(uC0 >> 16)) + pD * bf2f((unsigned short)(uD0 >> 16));
        v1 += pA * bf2f((unsigned short)(uA1 >> 16)) + pB * bf2f((unsigned short)(uB1 >> 16))
            + pC * bf2f((unsigned short)(uC1 >> 16)) + pD * bf2f((unsigned short)(uD1 >> 16));
        v2 += pA * bf2f((unsigned short)(uA2 >> 16)) + pB * bf2f((unsigned short)(uB2 >> 16))
            + pC * bf2f((unsigned short)(uC2 >> 16)) + pD * bf2f((unsigned short)(uD2 >> 16));
        wa0 += pA * wA.x + pB * wB.x + pC * wC.x + pD * wD.x;
        wa1 += pA * wA.y + pB * wB.y + pC * wC.y + pD * wD.y;
        wa2 += pA * wA.z + pB * wB.z + pC * wC.z + pD * wD.z;
        wa3 += pA * wA.w + pB * wB.w + pC * wC.w + pD * wD.w;
    }
    for (; p < end; ++p) {
        int2 se = csr2[p];
        size_t b = (size_t)se.x * 192 + d0;
        unsigned int u0 = kv[b], u1 = kv[b + 1], u2 = kv[b + 2];
        float4 w = ea4[se.y];
        float d = q0 * bf2f((unsigned short)u0) + q1 * bf2f((unsigned short)u1)
                + q2 * bf2f((unsigned short)u2);
#pragma unroll
        for (int off = 1; off < 16; off <<= 1) d += __shfl_xor(d, off);
        float pe = __expf(d + w.x * qe0 + w.y * qe1 + w.z * qe2 + w.w * qe3);
        den += pe;
        v0 += pe * bf2f((unsigned short)(u0 >> 16));
        v1 += pe * bf2f((unsigned short)(u1 >> 16));
        v2 += pe * bf2f((unsigned short)(u2 >> 16));
        wa0 += pe * w.x;
        wa1 += pe * w.y;
        wa2 += pe * w.z;
        wa3 += pe * w.w;
    }
    float inv = 1.f / (den + 1e-16f);
    float m0 = (v0 + wa0 * W[0][0] + wa1 * W[1][0] + wa2 * W[2][0] + wa3 * W[3][0]) * inv;
    float m1 = (v1 + wa0 * W[0][1] + wa1 * W[1][1] + wa2 * W[2][1] + wa3 * W[3][1]) * inv;
    float m2 = (v2 + wa0 * W[0][2] + wa1 * W[1][2] + wa2 * W[2][2] + wa3 * W[3][2]) * inv;
    size_t ob = (size_t)node * 192 + d0;
    msg_hi[ob]     = f2bf(m0);
    msg_hi[ob + 1] = f2bf(m1);
    msg_hi[ob + 2] = f2bf(m2);
}

// ---------------- edge head (round-6 version): reg A-fragments, swizzled sW -----------
__global__ __launch_bounds__(256, 2)
void edge_head_kernel(const unsigned short* __restrict__ hsd, const float* __restrict__ ea,
                      const int* __restrict__ src, const int* __restrict__ dst,
                      const float* __restrict__ W1e, const float* __restrict__ b1,
                      const unsigned short* __restrict__ W2hi,
                      const float* __restrict__ b2, const float* __restrict__ W3,
                      const float* __restrict__ b3, float* __restrict__ out) {
    __shared__ __align__(16) unsigned short sW[96 * 192];   // SBLK=24 blocks, swizzled
    __shared__ __align__(16) float sWe1[768];
    __shared__ __align__(16) float sB1[192];
    const int tid = threadIdx.x;
    const int wave = tid >> 6, lane = tid & 63;
    const int quad = lane >> 4, l16 = lane & 15;
    const int ebase = blockIdx.x * 64;

    for (int i = tid; i < 768; i += 256) sWe1[i] = W1e[i];
    if (tid < 192) sB1[tid] = b1[tid];
    for (int i = tid; i < 96 * 24; i += 256) {
        int n = i % 96, j = i / 96;
        *(uint4*)&sW[(n * 24 + (j ^ (n & 7))) * 8] = *(const uint4*)(W2hi + (size_t)n * 192 + j * 8);
    }

    const int e = ebase + wave * 16 + l16;        // this lane's edge
    const int s = src[e], d = dst[e];
    const float4 eav = *(const float4*)(ea + (size_t)e * 4);
    const unsigned short* hs_p = hsd + (size_t)s * 384 + quad * 8;
    const unsigned short* hd_p = hsd + (size_t)d * 384 + 192 + quad * 8;

    floatx4 acc[6];
#pragma unroll
    for (int nt = 0; nt < 6; ++nt) acc[nt] = (floatx4)0.0f;
    __syncthreads();

    ushort8 hs_c = *(const ushort8*)hs_p;
    ushort8 hd_c = *(const ushort8*)hd_p;
#pragma unroll
    for (int kc = 0; kc < 192; kc += 32) {
        ushort8 hs_n = hs_c, hd_n = hd_c;
        if (kc + 32 < 192) {
            hs_n = *(const ushort8*)(hs_p + kc + 32);
            hd_n = *(const ushort8*)(hd_p + kc + 32);
        }
        const int c0 = kc + quad * 8;
        float wb1[8], w0v[8], w1v[8], w2v[8], w3v[8];
        *(float4*)&wb1[0] = *(const float4*)&sB1[c0];
        *(float4*)&wb1[4] = *(const float4*)&sB1[c0 + 4];
        *(float4*)&w0v[0] = *(const float4*)&sWe1[c0];
        *(float4*)&w0v[4] = *(const float4*)&sWe1[c0 + 4];
        *(float4*)&w1v[0] = *(const float4*)&sWe1[192 + c0];
        *(float4*)&w1v[4] = *(const float4*)&sWe1[192 + c0 + 4];
        *(float4*)&w2v[0] = *(const float4*)&sWe1[384 + c0];
        *(float4*)&w2v[4] = *(const float4*)&sWe1[384 + c0 + 4];
        *(float4*)&w3v[0] = *(const float4*)&sWe1[576 + c0];
        *(float4*)&w3v[4] = *(const float4*)&sWe1[576 + c0 + 4];
        ushort8 ah;
#pragma unroll
        for (int j = 0; j < 8; ++j) {
            float ce = wb1[j] + eav.x * w0v[j] + eav.y * w1v[j]
                     + eav.z * w2v[j] + eav.w * w3v[j];
            float v = fmaxf(bf2f(hs_c[j]) + bf2f(hd_c[j]) + ce, 0.f);
            ah[j] = f2bf(v);
        }
        short8 ahs = *(short8*)&ah;
        const int jbase = kc / 8;
#pragma unroll
        for (int nt = 0; nt < 6; ++nt) {
            int jj = (jbase + quad) ^ (l16 & 7);
            short8 bh = *(const short8*)&sW[((nt * 16 + l16) * 24 + jj) * 8];
            acc[nt] = mfma16(ahs, bh, acc[nt]);
        }
        hs_c = hs_n; hd_c = hd_n;
    }

    float w3[6], bb2[6];
#pragma unroll
    for (int nt = 0; nt < 6; ++nt) {
        int col = nt * 16 + l16;
        w3[nt] = W3[col];
        bb2[nt] = b2[col];
    }
    float b3v = b3[0];
#pragma unroll
    for (int reg = 0; reg < 4; ++reg) {
        float sacc = 0.f;
#pragma unroll
        for (int nt = 0; nt < 6; ++nt) {
            float z = fmaxf(acc[nt][reg] + bb2[nt], 0.f);
            sacc = fmaf(z, w3[nt], sacc);
        }
#pragma unroll
        for (int off = 1; off < 16; off <<= 1) sacc += __shfl_xor(sacc, off);
        if (l16 == 0) out[ebase + wave * 16 + quad * 4 + reg] = sacc + b3v;
    }
}

extern "C" void kernel_launch(void* const* d_in, const int* in_sizes, int n_in,
                              void* d_out, int out_size, void* d_ws, size_t ws_size,
                              hipStream_t stream) {
    const float* x     = (const float*)d_in[0];
    const int*   eidx  = (const int*)d_in[1];
    const float* ea    = (const float*)d_in[2];
    const int*   batch = (const int*)d_in[3];
    const int*   gptr  = (const int*)d_in[4];
    const int*   tgid  = (const int*)d_in[5];
    const float* gp    = (const float*)d_in[6];
    const float* sp    = (const float*)d_in[7];
    const float* epp   = (const float*)d_in[8];
    const float* W_in  = (const float*)d_in[9];
    const float* b_in  = (const float*)d_in[10];
    const float* Wq    = (const float*)d_in[11];
    const float* Wk    = (const float*)d_in[12];
    const float* Wv    = (const float*)d_in[13];
    const float* We    = (const float*)d_in[14];
    const float* Wo    = (const float*)d_in[15];
    const float* bo    = (const float*)d_in[16];
    const float* ln1g  = (const float*)d_in[17];
    const float* ln1b  = (const float*)d_in[18];
    const float* Wf1   = (const float*)d_in[19];
    const float* bf1   = (const float*)d_in[20];
    const float* Wf2   = (const float*)d_in[21];
    const float* bf2   = (const float*)d_in[22];
    const float* ln2g  = (const float*)d_in[23];
    const float* ln2b  = (const float*)d_in[24];
    const float* We1   = (const float*)d_in[25];
    const float* be1   = (const float*)d_in[26];
    const float* We2   = (const float*)d_in[27];
    const float* be2   = (const float*)d_in[28];
    const float* We3   = (const float*)d_in[29];
    const float* be3   = (const float*)d_in[30];
    const int* src = eidx;
    const int* dst = eidx + N_EDGES;

    unsigned short* ub = (unsigned short*)d_ws;
    unsigned short* featH = ub;                  // 40000*32
    unsigned short* featL = ub + 1280000;
    unsigned short* hH    = ub + 2560000;        // 40000*192 each
    unsigned short* hL    = ub + 10240000;
    unsigned short* htH   = ub + 17920000;
    unsigned short* htL   = ub + 25600000;
    unsigned short* msgH  = ub + 33280000;
    unsigned short* rbuf  = ub + 48640000;       // 40000*768 region
    unsigned short* qB    = rbuf;                // 40000*192
    unsigned short* kvB   = rbuf + 7680000;      // 40000*384 interleaved k/v
    unsigned short* ffH   = rbuf;                // 40000*384 (after attn)
    unsigned short* hsdB  = rbuf;                // 40000*384
    unsigned short* wb    = ub + 79360000;       // WTOT
    int* ib   = (int*)(ub + 80343040);
    int* cnt  = ib;
    int* rowp = ib + 40000;
    int* curs = ib + 80004;
    int2* csr2 = (int2*)(ib + 120004);
    int* bsum  = ib + 920004;
    int* boffs = ib + 920044;

    hipMemsetAsync(cnt, 0, N_NODES * sizeof(int), stream);
    count_kernel<<<1563, 256, 0, stream>>>(dst, cnt, N_EDGES);
    scan1_kernel<<<40, 1024, 0, stream>>>(cnt, rowp, bsum, N_NODES);
    scan2_kernel<<<1, 64, 0, stream>>>(bsum, boffs, rowp, 40, N_NODES);
    scan3_kernel<<<40, 1024, 0, stream>>>(rowp, curs, boffs, N_NODES);
    scatter_kernel<<<1563, 256, 0, stream>>>(src, dst, curs, csr2, N_EDGES);
    feat_kernel<<<5000, 256, 0, stream>>>(x, batch, gptr, tgid, gp, sp, epp, featH, featL, N_NODES);
    prep_kernel<<<3840, 256, 0, stream>>>(W_in, Wq, Wk, Wv, Wo, Wf1, Wf2, We1, We2, wb);

    dim3 blk(256);
    // input projection: feat[40000, K=32 planes] @ W_in -> h planes (chunked path)
    mfma_gemm<0, 1, 96, 32, 2><<<dim3(313, 2), blk, 0, stream>>>(featH, featL, N_NODES, 32,
        wb + WOFF_WIN, b_in, nullptr, nullptr, nullptr, nullptr, hH, hL, 192);

    for (int l = 0; l < 3; ++l) {
        const unsigned short* wq = wb + WOFF_QKV + l * 110592;
        // fused qkv, A-stationary: q -> qB, k/v -> kvB interleaved (single-term A)
        mfma_gemm_astat<0, 0, 96, 6, 1, 6, 1><<<313, blk, 0, stream>>>(hH, hL, N_NODES,
            wq, nullptr, qB, kvB, 0);
        attn_kernel<<<10000, blk, 0, stream>>>(qB, kvB, ea, We + l * 768, csr2, rowp, msgH);
        // wo + residual + LN (msg single-plane -> TERMS=1)
        mfma_gemm<2, 1, 192, 96, 1><<<dim3(313, 1), blk, 0, stream>>>(msgH, msgH, N_NODES, 192,
            wb + WOFF_WO + l * 36864, bo + l * 192, hH, hL, ln1g + l * 192, ln1b + l * 192,
            htH, htL, 192);
        // ff1: relu, single-plane output
        mfma_gemm_astat<1, 0, 96, 4, 2, 6, 0><<<313, blk, 0, stream>>>(htH, htL, N_NODES,
            wb + WOFF_WF1 + l * 73728, bf1 + l * 384, ffH, nullptr, 384);
        // ff2 + residual + LN (ff single-plane -> TERMS=1)
        mfma_gemm<2, 1, 192, 96, 1><<<dim3(313, 1), blk, 0, stream>>>(ffH, ffH, N_NODES, 384,
            wb + WOFF_WF2 + l * 73728, bf2 + l * 192, htH, htL, ln2g + l * 192, ln2b + l * 192,
            hH, hL, 192);
    }

    // edge head pre-projections, A-stationary: [Hs|Hd] -> hsdB bf16 [N,384]
    mfma_gemm_astat<0, 0, 96, 4, 2, 6, 0><<<313, blk, 0, stream>>>(hH, hL, N_NODES,
        wb + WOFF_HSD, nullptr, hsdB, nullptr, 384);
    edge_head_kernel<<<6250, blk, 0, stream>>>(hsdB, ea, src, dst,
        We1 + 384 * 192, be1, wb + WOFF_WE2, be2, We3, be3, (float*)d_out);
}